// Round 1
// baseline (3203.213 us; speedup 1.0000x reference)
//
#include <hip/hip_runtime.h>
#include <stdint.h>

#define NNODES 50000
#define NEDGES 800000
#define FDIM 16
#define HDIM 128

static constexpr size_t NH  = (size_t)NNODES * HDIM;   // 6.4e6 elems
static constexpr size_t NHB = NH * sizeof(float);      // 25.6 MB

// workspace layout (all 16B aligned)
static constexpr size_t OFF_BUF0  = 0;
static constexpr size_t OFF_BUF1  = NHB;
static constexpr size_t OFF_BUF2  = 2 * NHB;
static constexpr size_t OFF_CNT   = 3 * NHB;                 // N x u32
static constexpr size_t OFF_WFOLD = OFF_CNT + 200704;        // 128*4 f32
static constexpr size_t OFF_BFOLD = OFF_WFOLD + 2048;        // 4 f32
static constexpr size_t OFF_FLAG  = OFF_BFOLD + 256;         // 1 int
static constexpr size_t OFF_SRC   = OFF_FLAG + 256;          // E x i32
static constexpr size_t OFF_DST   = OFF_SRC + (size_t)NEDGES * 4;

// ---------------- edge-index canonicalization (int32 or int64 input) --------
__global__ void k_detect(const int* __restrict__ raw, int* __restrict__ flag) {
  if (threadIdx.x == 0 && blockIdx.x == 0) {
    int is64 = 1;
    #pragma unroll
    for (int k = 1; k < 64; k += 2)
      if (raw[k] != 0) is64 = 0;   // int64 => high dwords of first values are 0
    *flag = is64;
  }
}

__global__ __launch_bounds__(256) void k_repack(const int* __restrict__ raw,
                                                const int* __restrict__ flag,
                                                int* __restrict__ src,
                                                int* __restrict__ dst) {
  const size_t e = (size_t)blockIdx.x * 256 + threadIdx.x;
  if (*flag) {
    src[e] = raw[2 * e];
    dst[e] = raw[2 * ((size_t)NEDGES + e)];
  } else {
    src[e] = raw[e];
    dst[e] = raw[NEDGES + e];
  }
}

__global__ __launch_bounds__(256) void k_count(const int* __restrict__ dst,
                                               unsigned* __restrict__ cnt) {
  const int e = blockIdx.x * 256 + threadIdx.x;
  atomicAdd(&cnt[dst[e]], 1u);
}

// ---------------- fold W22 @ Wf (128x4) and b22 @ Wf + bf -------------------
__global__ __launch_bounds__(512) void k_fold(const float* __restrict__ W22,
                                              const float* __restrict__ Wf,
                                              const float* __restrict__ b22,
                                              const float* __restrict__ bf,
                                              float* __restrict__ Wfold,
                                              float* __restrict__ bfold) {
  const int tid = threadIdx.x;       // 512 = 128 f x 4 o
  const int f = tid >> 2, o = tid & 3;
  float acc = 0.f;
  for (int h = 0; h < HDIM; ++h)
    acc = fmaf(W22[f * HDIM + h], Wf[h * 4 + o], acc);
  Wfold[tid] = acc;
  if (tid < 4) {
    float a = bf[tid];
    for (int h = 0; h < HDIM; ++h) a = fmaf(b22[h], Wf[h * 4 + tid], a);
    bfold[tid] = a;
  }
}

// ---------------- node projections: A = X@(Wa-Wb)+b1, B = X@Wb --------------
// 16-feature input version (layer 0)
__global__ __launch_bounds__(256) void k_node_ab16(const float* __restrict__ x,
                                                   const float* __restrict__ W1,
                                                   const float* __restrict__ b1,
                                                   float* __restrict__ A,
                                                   float* __restrict__ B) {
  __shared__ float s_x[16 * FDIM];
  const int tid = threadIdx.x;
  const int nb = blockIdx.x * 16;
  s_x[tid] = x[(size_t)nb * FDIM + tid];   // 256 floats, coalesced
  __syncthreads();
  const int h = tid & 127;
  const int half = tid >> 7;
  float accA[8], accB[8];
  #pragma unroll
  for (int j = 0; j < 8; ++j) { accA[j] = 0.f; accB[j] = 0.f; }
  #pragma unroll 4
  for (int f = 0; f < FDIM; ++f) {
    const float wt = W1[f * HDIM + h];
    const float wb = W1[(f + FDIM) * HDIM + h];
    const float wd = wt - wb;
    #pragma unroll
    for (int j = 0; j < 8; ++j) {
      const float xv = s_x[(half * 8 + j) * FDIM + f];  // wave-broadcast
      accA[j] = fmaf(xv, wd, accA[j]);
      accB[j] = fmaf(xv, wb, accB[j]);
    }
  }
  const float bias = b1[h];
  #pragma unroll
  for (int j = 0; j < 8; ++j) {
    const size_t idx = (size_t)(nb + half * 8 + j) * HDIM + h;
    A[idx] = accA[j] + bias;
    B[idx] = accB[j];
  }
}

// 128-feature input version (layers 1, 2); W1 is [256][128]
__global__ __launch_bounds__(256) void k_node_ab(const float* __restrict__ hin,
                                                 const float* __restrict__ W1,
                                                 const float* __restrict__ b1,
                                                 float* __restrict__ A,
                                                 float* __restrict__ B) {
  __shared__ float s_h[16 * HDIM];
  const int tid = threadIdx.x;
  const int nb = blockIdx.x * 16;
  {
    const float4* hv = (const float4*)(hin + (size_t)nb * HDIM);
    float4* sv = (float4*)s_h;
    sv[tid] = hv[tid];
    sv[tid + 256] = hv[tid + 256];
  }
  __syncthreads();
  const int h = tid & 127;
  const int half = tid >> 7;
  float accA[8], accB[8];
  #pragma unroll
  for (int j = 0; j < 8; ++j) { accA[j] = 0.f; accB[j] = 0.f; }
  #pragma unroll 4
  for (int f = 0; f < HDIM; ++f) {
    const float wt = W1[f * HDIM + h];
    const float wb = W1[(f + HDIM) * HDIM + h];
    const float wd = wt - wb;
    #pragma unroll
    for (int j = 0; j < 8; ++j) {
      const float hv = s_h[(half * 8 + j) * HDIM + f];  // wave-broadcast
      accA[j] = fmaf(hv, wd, accA[j]);
      accB[j] = fmaf(hv, wb, accB[j]);
    }
  }
  const float bias = b1[h];
  #pragma unroll
  for (int j = 0; j < 8; ++j) {
    const size_t idx = (size_t)(nb + half * 8 + j) * HDIM + h;
    A[idx] = accA[j] + bias;
    B[idx] = accB[j];
  }
}

// ---------------- layer 0: per-edge GEMM + encoded atomicMax ----------------
// m_e = relu(A0[dst]+B0[src]) @ W02 + b02 ; segment-max via monotone uint enc.
__global__ __launch_bounds__(256) void k_edge_gemm_max(
    const float* __restrict__ A0, const float* __restrict__ B0,
    const int* __restrict__ src, const int* __restrict__ dst,
    const float* __restrict__ W2, const float* __restrict__ b2,
    unsigned* __restrict__ outenc) {
  __shared__ float s_w[64 * HDIM];   // W02 K-chunk [64][128]
  __shared__ float s_t[64 * 65];     // t tile [edge][k], pad 65
  __shared__ int s_dst[64];
  __shared__ int s_src[64];
  const int tid = threadIdx.x;
  const int eb = blockIdx.x * 64;
  if (tid < 64) s_dst[tid] = dst[eb + tid];
  else if (tid < 128) s_src[tid - 64] = src[eb + tid - 64];
  __syncthreads();

  float acc[4][8];
  #pragma unroll
  for (int i = 0; i < 4; ++i)
    #pragma unroll
    for (int j = 0; j < 8; ++j) acc[i][j] = 0.f;

  const int rowg = tid & 15;
  const int colg = tid >> 4;
  const int r0 = rowg * 4;
  const int c0 = colg * 8;

  for (int kc = 0; kc < 2; ++kc) {
    const int k0 = kc * 64;
    {  // stage W chunk: 8192 floats
      const float4* Wv = (const float4*)(W2 + (size_t)k0 * HDIM);
      float4* swv = (float4*)s_w;
      #pragma unroll
      for (int j = 0; j < 8; ++j) swv[tid + j * 256] = Wv[tid + j * 256];
    }
    // stage t chunk: 64 edges x 64 k, t = relu(A0[dst]+B0[src])
    #pragma unroll
    for (int j = 0; j < 4; ++j) {
      const int i = tid + j * 256;
      const int e = i >> 4;
      const int kq = (i & 15) * 4;
      const float4 a4 = *(const float4*)(A0 + (size_t)s_dst[e] * HDIM + k0 + kq);
      const float4 b4 = *(const float4*)(B0 + (size_t)s_src[e] * HDIM + k0 + kq);
      float* tr = s_t + e * 65 + kq;
      tr[0] = fmaxf(a4.x + b4.x, 0.f);
      tr[1] = fmaxf(a4.y + b4.y, 0.f);
      tr[2] = fmaxf(a4.z + b4.z, 0.f);
      tr[3] = fmaxf(a4.w + b4.w, 0.f);
    }
    __syncthreads();
    #pragma unroll 4
    for (int kk = 0; kk < 64; ++kk) {
      float tv[4];
      #pragma unroll
      for (int i = 0; i < 4; ++i) tv[i] = s_t[(r0 + i) * 65 + kk];
      const float4 w0 = *(const float4*)(s_w + kk * HDIM + c0);
      const float4 w1 = *(const float4*)(s_w + kk * HDIM + c0 + 4);
      const float w[8] = {w0.x, w0.y, w0.z, w0.w, w1.x, w1.y, w1.z, w1.w};
      #pragma unroll
      for (int i = 0; i < 4; ++i)
        #pragma unroll
        for (int j = 0; j < 8; ++j)
          acc[i][j] = fmaf(tv[i], w[j], acc[i][j]);
    }
    __syncthreads();
  }

  float bb[8];
  #pragma unroll
  for (int j = 0; j < 8; ++j) bb[j] = b2[c0 + j];
  #pragma unroll
  for (int i = 0; i < 4; ++i) {
    const int d = s_dst[r0 + i];
    unsigned* orow = outenc + (size_t)d * HDIM + c0;
    #pragma unroll
    for (int j = 0; j < 8; ++j) {
      const float m = acc[i][j] + bb[j];
      unsigned u = __float_as_uint(m);
      u = (u & 0x80000000u) ? ~u : (u | 0x80000000u);  // monotone encoding
      atomicMax(orow + j, u);
    }
  }
}

// decode encoded max in place -> relu(max) ; enc==0 (no edge) -> 0
__global__ __launch_bounds__(256) void k_decode(unsigned* __restrict__ buf) {
  const size_t i = (size_t)blockIdx.x * 256 + threadIdx.x;
  const unsigned u = buf[i];
  float v = 0.f;
  if (u & 0x80000000u) v = __uint_as_float(u ^ 0x80000000u);  // orig >= 0
  ((float*)buf)[i] = v;
}

// ---------------- mean layers: per-edge gather + relu + atomicAdd -----------
__global__ __launch_bounds__(256) void k_edge_mean(const float* __restrict__ A,
                                                   const float* __restrict__ B,
                                                   const int* __restrict__ src,
                                                   const int* __restrict__ dst,
                                                   float* __restrict__ S) {
  const int tid = threadIdx.x;
  const int e = blockIdx.x * 2 + (tid >> 7);
  const int h = tid & 127;
  const int d = dst[e];
  const int s = src[e];
  const float v = A[(size_t)d * HDIM + h] + B[(size_t)s * HDIM + h];
  atomicAdd(&S[(size_t)d * HDIM + h], fmaxf(v, 0.f));
}

// h2 = relu(mean @ W2 + b2), 0 for isolated nodes
__global__ __launch_bounds__(256) void k_node_mean_relu(
    const float* __restrict__ S, const unsigned* __restrict__ cnt,
    const float* __restrict__ W, const float* __restrict__ b,
    float* __restrict__ h2) {
  __shared__ float s_m[16 * HDIM];
  __shared__ float s_scale[16];
  __shared__ float s_alive[16];
  const int tid = threadIdx.x;
  const int nb = blockIdx.x * 16;
  if (tid < 16) {
    const unsigned c = cnt[nb + tid];
    s_scale[tid] = c ? 1.f / (float)c : 0.f;
    s_alive[tid] = c ? 1.f : 0.f;
  }
  __syncthreads();
  {
    const float4* Sv = (const float4*)(S + (size_t)nb * HDIM);
    float4* mv = (float4*)s_m;
    #pragma unroll
    for (int j = 0; j < 2; ++j) {
      const int i = tid + j * 256;
      float4 v = Sv[i];
      const float sc = s_scale[i >> 5];
      v.x *= sc; v.y *= sc; v.z *= sc; v.w *= sc;
      mv[i] = v;
    }
  }
  __syncthreads();
  const int h = tid & 127;
  const int half = tid >> 7;
  float acc[8];
  #pragma unroll
  for (int j = 0; j < 8; ++j) acc[j] = 0.f;
  #pragma unroll 4
  for (int f = 0; f < HDIM; ++f) {
    const float w = W[f * HDIM + h];
    #pragma unroll
    for (int j = 0; j < 8; ++j)
      acc[j] = fmaf(s_m[(half * 8 + j) * HDIM + f], w, acc[j]);
  }
  const float bias = b[h];
  #pragma unroll
  for (int j = 0; j < 8; ++j) {
    const int n = half * 8 + j;
    h2[(size_t)(nb + n) * HDIM + h] = fmaxf(acc[j] + bias, 0.f) * s_alive[n];
  }
}

// ---------------- final: out = (mean2 @ Wfold) + bfold ; isolated -> bf -----
__global__ __launch_bounds__(256) void k_final(const float* __restrict__ S2,
                                               const unsigned* __restrict__ cnt,
                                               const float* __restrict__ Wfold,
                                               const float* __restrict__ bfold,
                                               const float* __restrict__ bf,
                                               float* __restrict__ out) {
  const int n = blockIdx.x * 256 + threadIdx.x;
  if (n >= NNODES) return;
  const unsigned c = cnt[n];
  float4 o;
  if (c == 0) {
    o.x = bf[0]; o.y = bf[1]; o.z = bf[2]; o.w = bf[3];  // exact reference
  } else {
    const float inv = 1.f / (float)c;
    float a0 = 0.f, a1 = 0.f, a2 = 0.f, a3 = 0.f;
    const float4* row = (const float4*)(S2 + (size_t)n * HDIM);
    const float4* Wv = (const float4*)Wfold;
    #pragma unroll 4
    for (int fq = 0; fq < 32; ++fq) {
      const float4 s4 = row[fq];
      const float vs[4] = {s4.x, s4.y, s4.z, s4.w};
      #pragma unroll
      for (int i = 0; i < 4; ++i) {
        const float v = vs[i] * inv;
        const float4 wf = Wv[fq * 4 + i];
        a0 = fmaf(v, wf.x, a0);
        a1 = fmaf(v, wf.y, a1);
        a2 = fmaf(v, wf.z, a2);
        a3 = fmaf(v, wf.w, a3);
      }
    }
    o.x = a0 + bfold[0]; o.y = a1 + bfold[1];
    o.z = a2 + bfold[2]; o.w = a3 + bfold[3];
  }
  ((float4*)out)[n] = o;
}

// ----------------------------------------------------------------------------
extern "C" void kernel_launch(void* const* d_in, const int* in_sizes, int n_in,
                              void* d_out, int out_size, void* d_ws, size_t ws_size,
                              hipStream_t stream) {
  const float* x   = (const float*)d_in[0];
  // d_in[1] = edge_attr: unused in math (nan-check only in original fwd)
  const int*   eidx = (const int*)d_in[2];
  const float* W01 = (const float*)d_in[3];
  const float* b01 = (const float*)d_in[4];
  const float* W02 = (const float*)d_in[5];
  const float* b02 = (const float*)d_in[6];
  const float* W11 = (const float*)d_in[7];
  const float* b11 = (const float*)d_in[8];
  const float* W12 = (const float*)d_in[9];
  const float* b12 = (const float*)d_in[10];
  const float* W21 = (const float*)d_in[11];
  const float* b21 = (const float*)d_in[12];
  const float* W22 = (const float*)d_in[13];
  const float* b22 = (const float*)d_in[14];
  const float* Wf  = (const float*)d_in[15];
  const float* bf  = (const float*)d_in[16];
  float* out = (float*)d_out;
  char* ws = (char*)d_ws;

  float* buf0 = (float*)(ws + OFF_BUF0);
  float* buf1 = (float*)(ws + OFF_BUF1);
  float* buf2 = (float*)(ws + OFF_BUF2);
  unsigned* cnt = (unsigned*)(ws + OFF_CNT);
  float* Wfold = (float*)(ws + OFF_WFOLD);
  float* bfold = (float*)(ws + OFF_BFOLD);
  int* flag  = (int*)(ws + OFF_FLAG);
  int* src32 = (int*)(ws + OFF_SRC);
  int* dst32 = (int*)(ws + OFF_DST);

  k_detect<<<1, 64, 0, stream>>>(eidx, flag);
  k_repack<<<NEDGES / 256, 256, 0, stream>>>(eidx, flag, src32, dst32);
  hipMemsetAsync(cnt, 0, NNODES * sizeof(unsigned), stream);
  k_count<<<NEDGES / 256, 256, 0, stream>>>(dst32, cnt);
  k_fold<<<1, 512, 0, stream>>>(W22, Wf, b22, bf, Wfold, bfold);

  // layer 0 (max)
  k_node_ab16<<<NNODES / 16, 256, 0, stream>>>(x, W01, b01, buf0, buf1);
  hipMemsetAsync(buf2, 0, NHB, stream);
  k_edge_gemm_max<<<NEDGES / 64, 256, 0, stream>>>(buf0, buf1, src32, dst32,
                                                   W02, b02, (unsigned*)buf2);
  k_decode<<<(int)(NH / 256), 256, 0, stream>>>((unsigned*)buf2);  // h1 = buf2

  // layer 1 (mean)
  k_node_ab<<<NNODES / 16, 256, 0, stream>>>(buf2, W11, b11, buf0, buf1);
  hipMemsetAsync(buf2, 0, NHB, stream);
  k_edge_mean<<<NEDGES / 2, 256, 0, stream>>>(buf0, buf1, src32, dst32, buf2);
  k_node_mean_relu<<<NNODES / 16, 256, 0, stream>>>(buf2, cnt, W12, b12, buf0);  // h2 = buf0

  // layer 2 (mean) + final fc
  k_node_ab<<<NNODES / 16, 256, 0, stream>>>(buf0, W21, b21, buf1, buf2);
  hipMemsetAsync(buf0, 0, NHB, stream);
  k_edge_mean<<<NEDGES / 2, 256, 0, stream>>>(buf1, buf2, src32, dst32, buf0);
  k_final<<<(NNODES + 255) / 256, 256, 0, stream>>>(buf0, cnt, Wfold, bfold, bf, out);

  (void)in_sizes; (void)n_in; (void)out_size; (void)ws_size;
}

// Round 2
// 858.798 us; speedup vs baseline: 3.7299x; 3.7299x over previous
//
#include <hip/hip_runtime.h>
#include <stdint.h>

#define NNODES 50000
#define NEDGES 800000
#define FDIM 16
#define HDIM 128
#define NPAD 50176            // 98 * 512, padded node count for the scan
#define NCH 98                // scan chunks of 512

static constexpr size_t NH  = (size_t)NNODES * HDIM;   // 6.4e6 elems
static constexpr size_t NHB = NH * sizeof(float);      // 25.6 MB

// workspace layout (16B aligned)
static constexpr size_t OFF_BUF0  = 0;
static constexpr size_t OFF_BUF1  = NHB;
static constexpr size_t OFF_BUF2  = 2 * NHB;
static constexpr size_t OFF_CNT   = 3 * NHB;                  // NPAD x u32
static constexpr size_t OFF_CUR   = OFF_CNT + NPAD * 4;       // NPAD x u32 (end offsets after scatter)
static constexpr size_t OFF_CSUM  = OFF_CUR + NPAD * 4;       // NCH x u32 (pad 512)
static constexpr size_t OFF_COFF  = OFF_CSUM + 512;           // NCH x u32
static constexpr size_t OFF_WFOLD = OFF_COFF + 512;           // 128*4 f32
static constexpr size_t OFF_BFOLD = OFF_WFOLD + 2048;         // 4 f32
static constexpr size_t OFF_FLAG  = OFF_BFOLD + 256;          // 1 int
static constexpr size_t OFF_SSRC  = OFF_FLAG + 256;           // E x i32 (sorted by dst)
static constexpr size_t OFF_SDST  = OFF_SSRC + (size_t)NEDGES * 4;

__device__ inline unsigned enc_f32(float m) {
  unsigned u = __float_as_uint(m);
  return (u & 0x80000000u) ? ~u : (u | 0x80000000u);  // monotone encoding, enc>0 always
}

// ---------------- edge-index dtype detect (int64 vs int32) ------------------
__global__ void k_detect(const int* __restrict__ raw, int* __restrict__ flag) {
  if (threadIdx.x == 0 && blockIdx.x == 0) {
    int is64 = 1;
    #pragma unroll
    for (int k = 1; k < 64; k += 2)
      if (raw[k] != 0) is64 = 0;   // int64 => high dwords zero
    *flag = is64;
  }
}

__global__ __launch_bounds__(256) void k_count(const int* __restrict__ raw,
                                               const int* __restrict__ flag,
                                               unsigned* __restrict__ cnt) {
  const size_t e = (size_t)blockIdx.x * 256 + threadIdx.x;
  const int d = (*flag) ? raw[2 * ((size_t)NEDGES + e)] : raw[NEDGES + e];
  atomicAdd(&cnt[d], 1u);
}

// ---------------- prefix scan over cnt -> cursor (exclusive offsets) --------
__global__ __launch_bounds__(256) void k_scan1(const unsigned* __restrict__ cnt,
                                               unsigned* __restrict__ csum) {
  __shared__ unsigned s[256];
  const int t = threadIdx.x, b = blockIdx.x;
  s[t] = cnt[b * 512 + t] + cnt[b * 512 + 256 + t];
  __syncthreads();
  for (int off = 128; off; off >>= 1) {
    if (t < off) s[t] += s[t + off];
    __syncthreads();
  }
  if (t == 0) csum[b] = s[0];
}

__global__ void k_scan2(const unsigned* __restrict__ csum,
                        unsigned* __restrict__ coff) {
  if (threadIdx.x == 0) {
    unsigned r = 0;
    for (int i = 0; i < NCH; ++i) { coff[i] = r; r += csum[i]; }
  }
}

__global__ __launch_bounds__(256) void k_scan3(const unsigned* __restrict__ cnt,
                                               const unsigned* __restrict__ coff,
                                               unsigned* __restrict__ cursor) {
  __shared__ unsigned s[256];
  const int t = threadIdx.x, b = blockIdx.x;
  const int base = b * 512;
  const unsigned c0 = cnt[base + 2 * t], c1 = cnt[base + 2 * t + 1];
  s[t] = c0 + c1;
  __syncthreads();
  for (int off = 1; off < 256; off <<= 1) {
    unsigned v = s[t];
    if (t >= off) v += s[t - off];
    __syncthreads();
    s[t] = v;
    __syncthreads();
  }
  const unsigned o = coff[b] + s[t] - (c0 + c1);  // exclusive pair prefix
  cursor[base + 2 * t] = o;
  cursor[base + 2 * t + 1] = o + c0;
}

__global__ __launch_bounds__(256) void k_scatter(const int* __restrict__ raw,
                                                 const int* __restrict__ flag,
                                                 unsigned* __restrict__ cursor,
                                                 int* __restrict__ ssrc,
                                                 int* __restrict__ sdst) {
  const size_t e = (size_t)blockIdx.x * 256 + threadIdx.x;
  int s, d;
  if (*flag) { s = raw[2 * e]; d = raw[2 * ((size_t)NEDGES + e)]; }
  else       { s = raw[e];     d = raw[NEDGES + e]; }
  const unsigned p = atomicAdd(&cursor[d], 1u);  // cursor ends at segment END
  ssrc[p] = s;
  sdst[p] = d;
}

// ---------------- fold W22 @ Wf (128x4) and b22 @ Wf + bf -------------------
__global__ __launch_bounds__(512) void k_fold(const float* __restrict__ W22,
                                              const float* __restrict__ Wf,
                                              const float* __restrict__ b22,
                                              const float* __restrict__ bf,
                                              float* __restrict__ Wfold,
                                              float* __restrict__ bfold) {
  const int tid = threadIdx.x;       // 512 = 128 f x 4 o
  const int f = tid >> 2, o = tid & 3;
  float acc = 0.f;
  for (int h = 0; h < HDIM; ++h)
    acc = fmaf(W22[f * HDIM + h], Wf[h * 4 + o], acc);
  Wfold[tid] = acc;
  if (tid < 4) {
    float a = bf[tid];
    for (int h = 0; h < HDIM; ++h) a = fmaf(b22[h], Wf[h * 4 + tid], a);
    bfold[tid] = a;
  }
}

// ---------------- node projections: A = X@(Wa-Wb)+b1, B = X@Wb --------------
__global__ __launch_bounds__(256) void k_node_ab16(const float* __restrict__ x,
                                                   const float* __restrict__ W1,
                                                   const float* __restrict__ b1,
                                                   float* __restrict__ A,
                                                   float* __restrict__ B) {
  __shared__ float s_x[16 * FDIM];
  const int tid = threadIdx.x;
  const int nb = blockIdx.x * 16;
  s_x[tid] = x[(size_t)nb * FDIM + tid];
  __syncthreads();
  const int h = tid & 127;
  const int half = tid >> 7;
  float accA[8], accB[8];
  #pragma unroll
  for (int j = 0; j < 8; ++j) { accA[j] = 0.f; accB[j] = 0.f; }
  #pragma unroll 4
  for (int f = 0; f < FDIM; ++f) {
    const float wt = W1[f * HDIM + h];
    const float wb = W1[(f + FDIM) * HDIM + h];
    const float wd = wt - wb;
    #pragma unroll
    for (int j = 0; j < 8; ++j) {
      const float xv = s_x[(half * 8 + j) * FDIM + f];
      accA[j] = fmaf(xv, wd, accA[j]);
      accB[j] = fmaf(xv, wb, accB[j]);
    }
  }
  const float bias = b1[h];
  #pragma unroll
  for (int j = 0; j < 8; ++j) {
    const size_t idx = (size_t)(nb + half * 8 + j) * HDIM + h;
    A[idx] = accA[j] + bias;
    B[idx] = accB[j];
  }
}

__global__ __launch_bounds__(256) void k_node_ab(const float* __restrict__ hin,
                                                 const float* __restrict__ W1,
                                                 const float* __restrict__ b1,
                                                 float* __restrict__ A,
                                                 float* __restrict__ B) {
  __shared__ float s_h[16 * HDIM];
  const int tid = threadIdx.x;
  const int nb = blockIdx.x * 16;
  {
    const float4* hv = (const float4*)(hin + (size_t)nb * HDIM);
    float4* sv = (float4*)s_h;
    sv[tid] = hv[tid];
    sv[tid + 256] = hv[tid + 256];
  }
  __syncthreads();
  const int h = tid & 127;
  const int half = tid >> 7;
  float accA[8], accB[8];
  #pragma unroll
  for (int j = 0; j < 8; ++j) { accA[j] = 0.f; accB[j] = 0.f; }
  #pragma unroll 4
  for (int f = 0; f < HDIM; ++f) {
    const float wt = W1[f * HDIM + h];
    const float wb = W1[(f + HDIM) * HDIM + h];
    const float wd = wt - wb;
    #pragma unroll
    for (int j = 0; j < 8; ++j) {
      const float hv = s_h[(half * 8 + j) * HDIM + f];
      accA[j] = fmaf(hv, wd, accA[j]);
      accB[j] = fmaf(hv, wb, accB[j]);
    }
  }
  const float bias = b1[h];
  #pragma unroll
  for (int j = 0; j < 8; ++j) {
    const size_t idx = (size_t)(nb + half * 8 + j) * HDIM + h;
    A[idx] = accA[j] + bias;
    B[idx] = accB[j];
  }
}

// ---------------- layer 0: tiled per-edge GEMM + LDS segmented max ----------
// edges sorted by dst: per-column segmented max in LDS, few atomics at seams.
__global__ __launch_bounds__(256) void k_edge_gemm_max(
    const float* __restrict__ A0, const float* __restrict__ B0,
    const int* __restrict__ ssrc, const int* __restrict__ sdst,
    const float* __restrict__ W2, const float* __restrict__ b2,
    unsigned* __restrict__ outenc) {
  __shared__ float s_u[64 * 132];    // union: W chunk [64][128] | m tile [64][132]
  __shared__ float s_t[64 * 65];     // t tile [edge][k], pad 65
  __shared__ int s_dst[64];
  __shared__ int s_src[64];
  const int tid = threadIdx.x;
  const int eb = blockIdx.x * 64;
  if (tid < 64) s_dst[tid] = sdst[eb + tid];
  else if (tid < 128) s_src[tid - 64] = ssrc[eb + tid - 64];
  __syncthreads();

  float acc[4][8];
  #pragma unroll
  for (int i = 0; i < 4; ++i)
    #pragma unroll
    for (int j = 0; j < 8; ++j) acc[i][j] = 0.f;

  const int rowg = tid & 15;
  const int colg = tid >> 4;
  const int r0 = rowg * 4;
  const int c0 = colg * 8;

  for (int kc = 0; kc < 2; ++kc) {
    const int k0 = kc * 64;
    {  // stage W chunk (8192 floats) into s_u
      const float4* Wv = (const float4*)(W2 + (size_t)k0 * HDIM);
      float4* swv = (float4*)s_u;
      #pragma unroll
      for (int j = 0; j < 8; ++j) swv[tid + j * 256] = Wv[tid + j * 256];
    }
    // stage t chunk: t = relu(A0[dst]+B0[src]); sorted dst -> A rows L1-hot
    #pragma unroll
    for (int j = 0; j < 4; ++j) {
      const int i = tid + j * 256;
      const int e = i >> 4;
      const int kq = (i & 15) * 4;
      const float4 a4 = *(const float4*)(A0 + (size_t)s_dst[e] * HDIM + k0 + kq);
      const float4 b4 = *(const float4*)(B0 + (size_t)s_src[e] * HDIM + k0 + kq);
      float* tr = s_t + e * 65 + kq;
      tr[0] = fmaxf(a4.x + b4.x, 0.f);
      tr[1] = fmaxf(a4.y + b4.y, 0.f);
      tr[2] = fmaxf(a4.z + b4.z, 0.f);
      tr[3] = fmaxf(a4.w + b4.w, 0.f);
    }
    __syncthreads();
    #pragma unroll 4
    for (int kk = 0; kk < 64; ++kk) {
      float tv[4];
      #pragma unroll
      for (int i = 0; i < 4; ++i) tv[i] = s_t[(r0 + i) * 65 + kk];
      const float4 w0 = *(const float4*)(s_u + kk * HDIM + c0);
      const float4 w1 = *(const float4*)(s_u + kk * HDIM + c0 + 4);
      const float w[8] = {w0.x, w0.y, w0.z, w0.w, w1.x, w1.y, w1.z, w1.w};
      #pragma unroll
      for (int i = 0; i < 4; ++i)
        #pragma unroll
        for (int j = 0; j < 8; ++j)
          acc[i][j] = fmaf(tv[i], w[j], acc[i][j]);
    }
    __syncthreads();
  }

  // dump m tile to LDS (reuse s_u as [64][132])
  float bb[8];
  #pragma unroll
  for (int j = 0; j < 8; ++j) bb[j] = b2[c0 + j];
  #pragma unroll
  for (int i = 0; i < 4; ++i)
    #pragma unroll
    for (int j = 0; j < 8; ++j)
      s_u[(r0 + i) * 132 + c0 + j] = acc[i][j] + bb[j];
  __syncthreads();

  // per-column segmented max over sorted dst; 2 groups of 32 edges
  {
    const int g = tid >> 7;          // 0/1
    const int c = tid & 127;
    const int e0 = g * 32;
    int curd = s_dst[e0];
    float run = s_u[e0 * 132 + c];
    for (int e = e0 + 1; e < e0 + 32; ++e) {
      const int d = s_dst[e];        // wave-uniform branch
      const float v = s_u[e * 132 + c];
      if (d == curd) run = fmaxf(run, v);
      else {
        atomicMax(outenc + (size_t)curd * HDIM + c, enc_f32(run));
        curd = d; run = v;
      }
    }
    atomicMax(outenc + (size_t)curd * HDIM + c, enc_f32(run));
  }
}

// decode encoded max in place -> relu(max) ; enc==0 (no edge) -> 0
__global__ __launch_bounds__(256) void k_decode(unsigned* __restrict__ buf) {
  const size_t i = (size_t)blockIdx.x * 256 + threadIdx.x;
  const unsigned u = buf[i];
  float v = 0.f;
  if (u & 0x80000000u) v = __uint_as_float(u ^ 0x80000000u);  // orig >= 0
  ((float*)buf)[i] = v;
}

// ---------------- mean layers: node-centric CSR sum, zero atomics -----------
__global__ __launch_bounds__(256) void k_seg_mean(const float* __restrict__ A,
                                                  const float* __restrict__ B,
                                                  const int* __restrict__ ssrc,
                                                  const unsigned* __restrict__ endv,
                                                  const unsigned* __restrict__ cnt,
                                                  float* __restrict__ S) {
  const int tid = threadIdx.x;
  const int n = blockIdx.x * 2 + (tid >> 7);
  const int c = tid & 127;
  const unsigned end = endv[n];
  const unsigned deg = cnt[n];
  unsigned e = end - deg;
  const float a = A[(size_t)n * HDIM + c];
  float sum = 0.f;
  for (; e + 4 <= end; e += 4) {
    const int s0 = ssrc[e],     s1 = ssrc[e + 1];
    const int s2 = ssrc[e + 2], s3 = ssrc[e + 3];
    const float v0 = B[(size_t)s0 * HDIM + c];
    const float v1 = B[(size_t)s1 * HDIM + c];
    const float v2 = B[(size_t)s2 * HDIM + c];
    const float v3 = B[(size_t)s3 * HDIM + c];
    sum += fmaxf(a + v0, 0.f) + fmaxf(a + v1, 0.f) +
           fmaxf(a + v2, 0.f) + fmaxf(a + v3, 0.f);
  }
  for (; e < end; ++e)
    sum += fmaxf(a + B[(size_t)ssrc[e] * HDIM + c], 0.f);
  S[(size_t)n * HDIM + c] = sum;
}

// h2 = relu(mean @ W2 + b2), 0 for isolated nodes
__global__ __launch_bounds__(256) void k_node_mean_relu(
    const float* __restrict__ S, const unsigned* __restrict__ cnt,
    const float* __restrict__ W, const float* __restrict__ b,
    float* __restrict__ h2) {
  __shared__ float s_m[16 * HDIM];
  __shared__ float s_scale[16];
  __shared__ float s_alive[16];
  const int tid = threadIdx.x;
  const int nb = blockIdx.x * 16;
  if (tid < 16) {
    const unsigned c = cnt[nb + tid];
    s_scale[tid] = c ? 1.f / (float)c : 0.f;
    s_alive[tid] = c ? 1.f : 0.f;
  }
  __syncthreads();
  {
    const float4* Sv = (const float4*)(S + (size_t)nb * HDIM);
    float4* mv = (float4*)s_m;
    #pragma unroll
    for (int j = 0; j < 2; ++j) {
      const int i = tid + j * 256;
      float4 v = Sv[i];
      const float sc = s_scale[i >> 5];
      v.x *= sc; v.y *= sc; v.z *= sc; v.w *= sc;
      mv[i] = v;
    }
  }
  __syncthreads();
  const int h = tid & 127;
  const int half = tid >> 7;
  float acc[8];
  #pragma unroll
  for (int j = 0; j < 8; ++j) acc[j] = 0.f;
  #pragma unroll 4
  for (int f = 0; f < HDIM; ++f) {
    const float w = W[f * HDIM + h];
    #pragma unroll
    for (int j = 0; j < 8; ++j)
      acc[j] = fmaf(s_m[(half * 8 + j) * HDIM + f], w, acc[j]);
  }
  const float bias = b[h];
  #pragma unroll
  for (int j = 0; j < 8; ++j) {
    const int n = half * 8 + j;
    h2[(size_t)(nb + n) * HDIM + h] = fmaxf(acc[j] + bias, 0.f) * s_alive[n];
  }
}

// ---------------- final: out = (mean2 @ Wfold) + bfold ; isolated -> bf -----
__global__ __launch_bounds__(256) void k_final(const float* __restrict__ S2,
                                               const unsigned* __restrict__ cnt,
                                               const float* __restrict__ Wfold,
                                               const float* __restrict__ bfold,
                                               const float* __restrict__ bf,
                                               float* __restrict__ out) {
  const int n = blockIdx.x * 256 + threadIdx.x;
  if (n >= NNODES) return;
  const unsigned c = cnt[n];
  float4 o;
  if (c == 0) {
    o.x = bf[0]; o.y = bf[1]; o.z = bf[2]; o.w = bf[3];
  } else {
    const float inv = 1.f / (float)c;
    float a0 = 0.f, a1 = 0.f, a2 = 0.f, a3 = 0.f;
    const float4* row = (const float4*)(S2 + (size_t)n * HDIM);
    const float4* Wv = (const float4*)Wfold;
    #pragma unroll 4
    for (int fq = 0; fq < 32; ++fq) {
      const float4 s4 = row[fq];
      const float vs[4] = {s4.x, s4.y, s4.z, s4.w};
      #pragma unroll
      for (int i = 0; i < 4; ++i) {
        const float v = vs[i] * inv;
        const float4 wf = Wv[fq * 4 + i];
        a0 = fmaf(v, wf.x, a0);
        a1 = fmaf(v, wf.y, a1);
        a2 = fmaf(v, wf.z, a2);
        a3 = fmaf(v, wf.w, a3);
      }
    }
    o.x = a0 + bfold[0]; o.y = a1 + bfold[1];
    o.z = a2 + bfold[2]; o.w = a3 + bfold[3];
  }
  ((float4*)out)[n] = o;
}

// ----------------------------------------------------------------------------
extern "C" void kernel_launch(void* const* d_in, const int* in_sizes, int n_in,
                              void* d_out, int out_size, void* d_ws, size_t ws_size,
                              hipStream_t stream) {
  const float* x   = (const float*)d_in[0];
  // d_in[1] = edge_attr: unused in math
  const int*   eidx = (const int*)d_in[2];
  const float* W01 = (const float*)d_in[3];
  const float* b01 = (const float*)d_in[4];
  const float* W02 = (const float*)d_in[5];
  const float* b02 = (const float*)d_in[6];
  const float* W11 = (const float*)d_in[7];
  const float* b11 = (const float*)d_in[8];
  const float* W12 = (const float*)d_in[9];
  const float* b12 = (const float*)d_in[10];
  const float* W21 = (const float*)d_in[11];
  const float* b21 = (const float*)d_in[12];
  const float* W22 = (const float*)d_in[13];
  const float* b22 = (const float*)d_in[14];
  const float* Wf  = (const float*)d_in[15];
  const float* bf  = (const float*)d_in[16];
  float* out = (float*)d_out;
  char* ws = (char*)d_ws;

  float* buf0 = (float*)(ws + OFF_BUF0);
  float* buf1 = (float*)(ws + OFF_BUF1);
  float* buf2 = (float*)(ws + OFF_BUF2);
  unsigned* cnt    = (unsigned*)(ws + OFF_CNT);
  unsigned* cursor = (unsigned*)(ws + OFF_CUR);
  unsigned* csum   = (unsigned*)(ws + OFF_CSUM);
  unsigned* coff   = (unsigned*)(ws + OFF_COFF);
  float* Wfold = (float*)(ws + OFF_WFOLD);
  float* bfold = (float*)(ws + OFF_BFOLD);
  int* flag  = (int*)(ws + OFF_FLAG);
  int* ssrc  = (int*)(ws + OFF_SSRC);
  int* sdst  = (int*)(ws + OFF_SDST);

  // ---- counting sort of edges by dst (CSR) ----
  k_detect<<<1, 64, 0, stream>>>(eidx, flag);
  hipMemsetAsync(cnt, 0, NPAD * sizeof(unsigned), stream);
  k_count<<<NEDGES / 256, 256, 0, stream>>>(eidx, flag, cnt);
  k_scan1<<<NCH, 256, 0, stream>>>(cnt, csum);
  k_scan2<<<1, 64, 0, stream>>>(csum, coff);
  k_scan3<<<NCH, 256, 0, stream>>>(cnt, coff, cursor);
  k_scatter<<<NEDGES / 256, 256, 0, stream>>>(eidx, flag, cursor, ssrc, sdst);
  // after scatter: cursor[n] == segment end offset of node n
  k_fold<<<1, 512, 0, stream>>>(W22, Wf, b22, bf, Wfold, bfold);

  // ---- layer 0 (max aggr) ----
  k_node_ab16<<<NNODES / 16, 256, 0, stream>>>(x, W01, b01, buf0, buf1);
  hipMemsetAsync(buf2, 0, NHB, stream);
  k_edge_gemm_max<<<NEDGES / 64, 256, 0, stream>>>(buf0, buf1, ssrc, sdst,
                                                   W02, b02, (unsigned*)buf2);
  k_decode<<<(int)(NH / 256), 256, 0, stream>>>((unsigned*)buf2);  // h1 = buf2

  // ---- layer 1 (mean aggr) ----
  k_node_ab<<<NNODES / 16, 256, 0, stream>>>(buf2, W11, b11, buf0, buf1);
  k_seg_mean<<<NNODES / 2, 256, 0, stream>>>(buf0, buf1, ssrc, cursor, cnt, buf2);
  k_node_mean_relu<<<NNODES / 16, 256, 0, stream>>>(buf2, cnt, W12, b12, buf0);  // h2

  // ---- layer 2 (mean aggr) + final fc ----
  k_node_ab<<<NNODES / 16, 256, 0, stream>>>(buf0, W21, b21, buf1, buf2);
  k_seg_mean<<<NNODES / 2, 256, 0, stream>>>(buf1, buf2, ssrc, cursor, cnt, buf0);
  k_final<<<(NNODES + 255) / 256, 256, 0, stream>>>(buf0, cnt, Wfold, bfold, bf, out);

  (void)in_sizes; (void)n_in; (void)out_size; (void)ws_size;
}

// Round 3
// 636.344 us; speedup vs baseline: 5.0338x; 1.3496x over previous
//
#include <hip/hip_runtime.h>
#include <stdint.h>

#define NNODES 50000
#define NEDGES 800000
#define FDIM 16
#define HDIM 128
#define NPAD 50176            // 98 * 512, padded node count for the scan
#define NCH 98                // scan chunks of 512

typedef __attribute__((ext_vector_type(8))) short short8;
typedef __attribute__((ext_vector_type(4))) float f32x4;

static constexpr size_t NH  = (size_t)NNODES * HDIM;   // 6.4e6 elems
static constexpr size_t NHB = NH * sizeof(float);      // 25.6 MB

// workspace layout (16B aligned)
static constexpr size_t OFF_BUF0  = 0;
static constexpr size_t OFF_BUF1  = NHB;
static constexpr size_t OFF_BUF2  = 2 * NHB;
static constexpr size_t OFF_CNT   = 3 * NHB;                  // NPAD x u32
static constexpr size_t OFF_CUR   = OFF_CNT + NPAD * 4;       // NPAD x u32 (end offsets after scatter)
static constexpr size_t OFF_CSUM  = OFF_CUR + NPAD * 4;       // NCH x u32 (pad 512)
static constexpr size_t OFF_COFF  = OFF_CSUM + 512;           // NCH x u32
static constexpr size_t OFF_WFOLD = OFF_COFF + 512;           // 128*4 f32
static constexpr size_t OFF_BFOLD = OFF_WFOLD + 2048;         // 4 f32
static constexpr size_t OFF_FLAG  = OFF_BFOLD + 256;          // 1 int
static constexpr size_t OFF_SSRC  = OFF_FLAG + 256;           // E x i32 (sorted by dst)
static constexpr size_t OFF_SDST  = OFF_SSRC + (size_t)NEDGES * 4;
static constexpr size_t OFF_WHI   = OFF_SDST + (size_t)NEDGES * 4;  // 16384 bf16 = 32 KB
static constexpr size_t OFF_WLO   = OFF_WHI + 32768;                // 32 KB

__device__ inline unsigned enc_f32(float m) {
  unsigned u = __float_as_uint(m);
  return (u & 0x80000000u) ? ~u : (u | 0x80000000u);  // monotone encoding, enc>0 always
}

// rne split of fp32 into bf16 hi + bf16 lo
__device__ inline void bf16_split(float v, ushort& h, ushort& l) {
  unsigned u = __float_as_uint(v);
  unsigned hb = (u + 0x7fffu + ((u >> 16) & 1u)) & 0xffff0000u;
  h = (ushort)(hb >> 16);
  float r = v - __uint_as_float(hb);
  unsigned ur = __float_as_uint(r);
  l = (ushort)((ur + 0x7fffu + ((ur >> 16) & 1u)) >> 16);
}

// ---------------- edge-index dtype detect (int64 vs int32) ------------------
__global__ void k_detect(const int* __restrict__ raw, int* __restrict__ flag) {
  if (threadIdx.x == 0 && blockIdx.x == 0) {
    int is64 = 1;
    #pragma unroll
    for (int k = 1; k < 64; k += 2)
      if (raw[k] != 0) is64 = 0;   // int64 => high dwords zero
    *flag = is64;
  }
}

__global__ __launch_bounds__(256) void k_count(const int* __restrict__ raw,
                                               const int* __restrict__ flag,
                                               unsigned* __restrict__ cnt) {
  const size_t e = (size_t)blockIdx.x * 256 + threadIdx.x;
  const int d = (*flag) ? raw[2 * ((size_t)NEDGES + e)] : raw[NEDGES + e];
  atomicAdd(&cnt[d], 1u);
}

// ---------------- prefix scan over cnt -> cursor (exclusive offsets) --------
__global__ __launch_bounds__(256) void k_scan1(const unsigned* __restrict__ cnt,
                                               unsigned* __restrict__ csum) {
  __shared__ unsigned s[256];
  const int t = threadIdx.x, b = blockIdx.x;
  s[t] = cnt[b * 512 + t] + cnt[b * 512 + 256 + t];
  __syncthreads();
  for (int off = 128; off; off >>= 1) {
    if (t < off) s[t] += s[t + off];
    __syncthreads();
  }
  if (t == 0) csum[b] = s[0];
}

__global__ void k_scan2(const unsigned* __restrict__ csum,
                        unsigned* __restrict__ coff) {
  if (threadIdx.x == 0) {
    unsigned r = 0;
    for (int i = 0; i < NCH; ++i) { coff[i] = r; r += csum[i]; }
  }
}

__global__ __launch_bounds__(256) void k_scan3(const unsigned* __restrict__ cnt,
                                               const unsigned* __restrict__ coff,
                                               unsigned* __restrict__ cursor) {
  __shared__ unsigned s[256];
  const int t = threadIdx.x, b = blockIdx.x;
  const int base = b * 512;
  const unsigned c0 = cnt[base + 2 * t], c1 = cnt[base + 2 * t + 1];
  s[t] = c0 + c1;
  __syncthreads();
  for (int off = 1; off < 256; off <<= 1) {
    unsigned v = s[t];
    if (t >= off) v += s[t - off];
    __syncthreads();
    s[t] = v;
    __syncthreads();
  }
  const unsigned o = coff[b] + s[t] - (c0 + c1);  // exclusive pair prefix
  cursor[base + 2 * t] = o;
  cursor[base + 2 * t + 1] = o + c0;
}

__global__ __launch_bounds__(256) void k_scatter(const int* __restrict__ raw,
                                                 const int* __restrict__ flag,
                                                 unsigned* __restrict__ cursor,
                                                 int* __restrict__ ssrc,
                                                 int* __restrict__ sdst) {
  const size_t e = (size_t)blockIdx.x * 256 + threadIdx.x;
  int s, d;
  if (*flag) { s = raw[2 * e]; d = raw[2 * ((size_t)NEDGES + e)]; }
  else       { s = raw[e];     d = raw[NEDGES + e]; }
  const unsigned p = atomicAdd(&cursor[d], 1u);  // cursor ends at segment END
  ssrc[p] = s;
  sdst[p] = d;
}

// ---------------- fold W22 @ Wf (128x4) and b22 @ Wf + bf -------------------
__global__ __launch_bounds__(512) void k_fold(const float* __restrict__ W22,
                                              const float* __restrict__ Wf,
                                              const float* __restrict__ b22,
                                              const float* __restrict__ bf,
                                              float* __restrict__ Wfold,
                                              float* __restrict__ bfold) {
  const int tid = threadIdx.x;       // 512 = 128 f x 4 o
  const int f = tid >> 2, o = tid & 3;
  float acc = 0.f;
  for (int h = 0; h < HDIM; ++h)
    acc = fmaf(W22[f * HDIM + h], Wf[h * 4 + o], acc);
  Wfold[tid] = acc;
  if (tid < 4) {
    float a = bf[tid];
    for (int h = 0; h < HDIM; ++h) a = fmaf(b22[h], Wf[h * 4 + tid], a);
    bfold[tid] = a;
  }
}

// ---------------- W02 prep: transpose + bf16 hi/lo split, frag-packed -------
// unit(ct,ks,kg,row) = ((ct*4+ks)*4+kg)*16 + row ; each unit = 8 bf16 (16 B):
//   Wt[col = ct*16+row][k = ks*32+kg*8 .. +7] where Wt = W02^T
__global__ __launch_bounds__(256) void k_prepw(const float* __restrict__ W2,
                                               ushort* __restrict__ Whi,
                                               ushort* __restrict__ Wlo) {
  const int gid = blockIdx.x * 256 + threadIdx.x;   // 0..2047
  const int row = gid & 15;
  const int kg  = (gid >> 4) & 3;
  const int ks  = (gid >> 6) & 3;
  const int ct  = gid >> 8;
  const int col = ct * 16 + row;
  const int k0  = ks * 32 + kg * 8;
  short8 hv, lv;
  #pragma unroll
  for (int j = 0; j < 8; ++j) {
    ushort h, l;
    bf16_split(W2[(size_t)(k0 + j) * HDIM + col], h, l);
    hv[j] = (short)h; lv[j] = (short)l;
  }
  *(short8*)(Whi + (size_t)gid * 8) = hv;
  *(short8*)(Wlo + (size_t)gid * 8) = lv;
}

// ---------------- node projections: A = X@(Wa-Wb)+b1, B = X@Wb --------------
__global__ __launch_bounds__(256) void k_node_ab16(const float* __restrict__ x,
                                                   const float* __restrict__ W1,
                                                   const float* __restrict__ b1,
                                                   float* __restrict__ A,
                                                   float* __restrict__ B) {
  __shared__ float s_x[16 * FDIM];
  const int tid = threadIdx.x;
  const int nb = blockIdx.x * 16;
  s_x[tid] = x[(size_t)nb * FDIM + tid];
  __syncthreads();
  const int h = tid & 127;
  const int half = tid >> 7;
  float accA[8], accB[8];
  #pragma unroll
  for (int j = 0; j < 8; ++j) { accA[j] = 0.f; accB[j] = 0.f; }
  #pragma unroll 4
  for (int f = 0; f < FDIM; ++f) {
    const float wt = W1[f * HDIM + h];
    const float wb = W1[(f + FDIM) * HDIM + h];
    const float wd = wt - wb;
    #pragma unroll
    for (int j = 0; j < 8; ++j) {
      const float xv = s_x[(half * 8 + j) * FDIM + f];
      accA[j] = fmaf(xv, wd, accA[j]);
      accB[j] = fmaf(xv, wb, accB[j]);
    }
  }
  const float bias = b1[h];
  #pragma unroll
  for (int j = 0; j < 8; ++j) {
    const size_t idx = (size_t)(nb + half * 8 + j) * HDIM + h;
    A[idx] = accA[j] + bias;
    B[idx] = accB[j];
  }
}

__global__ __launch_bounds__(256) void k_node_ab(const float* __restrict__ hin,
                                                 const float* __restrict__ W1,
                                                 const float* __restrict__ b1,
                                                 float* __restrict__ A,
                                                 float* __restrict__ B) {
  __shared__ float s_h[16 * HDIM];
  const int tid = threadIdx.x;
  const int nb = blockIdx.x * 16;
  {
    const float4* hv = (const float4*)(hin + (size_t)nb * HDIM);
    float4* sv = (float4*)s_h;
    sv[tid] = hv[tid];
    sv[tid + 256] = hv[tid + 256];
  }
  __syncthreads();
  const int h = tid & 127;
  const int half = tid >> 7;
  float accA[8], accB[8];
  #pragma unroll
  for (int j = 0; j < 8; ++j) { accA[j] = 0.f; accB[j] = 0.f; }
  #pragma unroll 4
  for (int f = 0; f < HDIM; ++f) {
    const float wt = W1[f * HDIM + h];
    const float wb = W1[(f + HDIM) * HDIM + h];
    const float wd = wt - wb;
    #pragma unroll
    for (int j = 0; j < 8; ++j) {
      const float hv = s_h[(half * 8 + j) * HDIM + f];
      accA[j] = fmaf(hv, wd, accA[j]);
      accB[j] = fmaf(hv, wb, accB[j]);
    }
  }
  const float bias = b1[h];
  #pragma unroll
  for (int j = 0; j < 8; ++j) {
    const size_t idx = (size_t)(nb + half * 8 + j) * HDIM + h;
    A[idx] = accA[j] + bias;
    B[idx] = accB[j];
  }
}

// ---------------- layer 0: split-bf16 MFMA edge GEMM + LDS segmented max ----
// m_e = relu(A0[dst]+B0[src]) @ W02 + b02, segment-max over sorted dst.
// t split hi/lo bf16; t@W ~= th@Wh + th@Wl + tl@Wh via mfma_f32_16x16x32_bf16.
__global__ __launch_bounds__(256) void k_edge_l0_mfma(
    const float* __restrict__ A0, const float* __restrict__ B0,
    const int* __restrict__ ssrc, const int* __restrict__ sdst,
    const ushort* __restrict__ Whi, const ushort* __restrict__ Wlo,
    const float* __restrict__ b2, unsigned* __restrict__ outenc) {
  // union: t-frags (32 KB) then per-wave m tiles (33.8 KB)
  __shared__ __align__(16) char s_un[4 * 64 * 33 * 4];
  __shared__ int s_dstA[64];
  __shared__ int s_srcA[64];
  ushort* s_thi = (ushort*)s_un;            // 64*128 bf16, swizzled 16B units
  ushort* s_tlo = (ushort*)(s_un + 16384);
  float*  s_m   = (float*)s_un;             // [4 waves][64][33] after barrier

  const int tid = threadIdx.x;
  const int eb = blockIdx.x * 64;
  if (tid < 64) s_dstA[tid] = sdst[eb + tid];
  else if (tid < 128) s_srcA[tid - 64] = ssrc[eb + tid - 64];
  __syncthreads();

  // ---- stage t = relu(A0[dst]+B0[src]) as hi/lo bf16 fragments ----
  // item: e = idx>>4 (edge row), kg8 = idx&15 (8-k group); 16 lanes/edge row.
  // LDS 16B-unit address: e*16 + (kg8 ^ (e&15))  (XOR swizzle, both sides)
  #pragma unroll
  for (int it = 0; it < 4; ++it) {
    const int idx = tid + it * 256;
    const int e = idx >> 4;
    const int kg8 = idx & 15;
    const int k0 = kg8 * 8;
    const float* ap = A0 + (size_t)s_dstA[e] * HDIM + k0;
    const float* bp = B0 + (size_t)s_srcA[e] * HDIM + k0;
    const float4 a0 = *(const float4*)ap;
    const float4 a1 = *(const float4*)(ap + 4);
    const float4 b0 = *(const float4*)bp;
    const float4 b1 = *(const float4*)(bp + 4);
    float v[8] = {a0.x + b0.x, a0.y + b0.y, a0.z + b0.z, a0.w + b0.w,
                  a1.x + b1.x, a1.y + b1.y, a1.z + b1.z, a1.w + b1.w};
    short8 hv, lv;
    #pragma unroll
    for (int j = 0; j < 8; ++j) {
      const float vv = fmaxf(v[j], 0.f);
      ushort h, l;
      bf16_split(vv, h, l);
      hv[j] = (short)h; lv[j] = (short)l;
    }
    const int unit = e * 16 + (kg8 ^ (e & 15));
    *(short8*)(s_thi + unit * 8) = hv;
    *(short8*)(s_tlo + unit * 8) = lv;
  }
  __syncthreads();

  // ---- MFMA: wave w computes all 64 rows x cols [w*32, w*32+32) ----
  const int l15 = tid & 15;
  const int l4  = (tid >> 4) & 3;
  const int w   = tid >> 6;

  f32x4 acc[4][2];
  #pragma unroll
  for (int rt = 0; rt < 4; ++rt)
    #pragma unroll
    for (int c = 0; c < 2; ++c)
      #pragma unroll
      for (int r = 0; r < 4; ++r) acc[rt][c][r] = 0.f;

  #pragma unroll
  for (int ks = 0; ks < 4; ++ks) {
    short8 wh[2], wl[2];
    #pragma unroll
    for (int ctl = 0; ctl < 2; ++ctl) {
      const int ct_g = w * 2 + ctl;
      const size_t u = ((size_t)(((ct_g * 4 + ks) * 4 + l4) * 16 + l15)) * 8;
      wh[ctl] = *(const short8*)(Whi + u);
      wl[ctl] = *(const short8*)(Wlo + u);
    }
    #pragma unroll
    for (int rt = 0; rt < 4; ++rt) {
      const int e = rt * 16 + l15;
      const int unit = e * 16 + ((ks * 4 + l4) ^ l15);
      const short8 ah = *(const short8*)(s_thi + unit * 8);
      const short8 al = *(const short8*)(s_tlo + unit * 8);
      #pragma unroll
      for (int ctl = 0; ctl < 2; ++ctl) {
        acc[rt][ctl] = __builtin_amdgcn_mfma_f32_16x16x32_bf16(al, wh[ctl], acc[rt][ctl], 0, 0, 0);
        acc[rt][ctl] = __builtin_amdgcn_mfma_f32_16x16x32_bf16(ah, wl[ctl], acc[rt][ctl], 0, 0, 0);
        acc[rt][ctl] = __builtin_amdgcn_mfma_f32_16x16x32_bf16(ah, wh[ctl], acc[rt][ctl], 0, 0, 0);
      }
    }
  }
  __syncthreads();   // all waves done reading t-frags; s_un becomes s_m

  // ---- dump m (+bias) to per-wave [64][33] tile, then segmented max ----
  const float bb0 = b2[w * 32 + l15];
  const float bb1 = b2[w * 32 + 16 + l15];
  float* sm = s_m + w * (64 * 33);
  #pragma unroll
  for (int rt = 0; rt < 4; ++rt)
    #pragma unroll
    for (int ctl = 0; ctl < 2; ++ctl)
      #pragma unroll
      for (int r = 0; r < 4; ++r)
        sm[(rt * 16 + l4 * 4 + r) * 33 + ctl * 16 + l15] =
            acc[rt][ctl][r] + (ctl ? bb1 : bb0);
  __syncthreads();

  {
    const int l = tid & 63;
    const int col = l & 31;            // wave-local col; global = w*32+col
    const int g = l >> 5;              // edge half
    const int e0 = g * 32;
    int curd = s_dstA[e0];
    float run = sm[e0 * 33 + col];
    for (int e = e0 + 1; e < e0 + 32; ++e) {
      const int d = s_dstA[e];         // wave-uniform branch
      const float v = sm[e * 33 + col];
      if (d == curd) run = fmaxf(run, v);
      else {
        atomicMax(outenc + (size_t)curd * HDIM + w * 32 + col, enc_f32(run));
        curd = d; run = v;
      }
    }
    atomicMax(outenc + (size_t)curd * HDIM + w * 32 + col, enc_f32(run));
  }
}

// decode encoded max in place -> relu(max) ; enc==0 (no edge) -> 0
__global__ __launch_bounds__(256) void k_decode(unsigned* __restrict__ buf) {
  const size_t i = (size_t)blockIdx.x * 256 + threadIdx.x;
  const unsigned u = buf[i];
  float v = 0.f;
  if (u & 0x80000000u) v = __uint_as_float(u ^ 0x80000000u);  // orig >= 0
  ((float*)buf)[i] = v;
}

// ---------------- mean layers: node-centric CSR sum, zero atomics -----------
__global__ __launch_bounds__(256) void k_seg_mean(const float* __restrict__ A,
                                                  const float* __restrict__ B,
                                                  const int* __restrict__ ssrc,
                                                  const unsigned* __restrict__ endv,
                                                  const unsigned* __restrict__ cnt,
                                                  float* __restrict__ S) {
  const int tid = threadIdx.x;
  const int n = blockIdx.x * 2 + (tid >> 7);
  const int c = tid & 127;
  const unsigned end = endv[n];
  const unsigned deg = cnt[n];
  unsigned e = end - deg;
  const float a = A[(size_t)n * HDIM + c];
  float sum = 0.f;
  for (; e + 4 <= end; e += 4) {
    const int s0 = ssrc[e],     s1 = ssrc[e + 1];
    const int s2 = ssrc[e + 2], s3 = ssrc[e + 3];
    const float v0 = B[(size_t)s0 * HDIM + c];
    const float v1 = B[(size_t)s1 * HDIM + c];
    const float v2 = B[(size_t)s2 * HDIM + c];
    const float v3 = B[(size_t)s3 * HDIM + c];
    sum += fmaxf(a + v0, 0.f) + fmaxf(a + v1, 0.f) +
           fmaxf(a + v2, 0.f) + fmaxf(a + v3, 0.f);
  }
  for (; e < end; ++e)
    sum += fmaxf(a + B[(size_t)ssrc[e] * HDIM + c], 0.f);
  S[(size_t)n * HDIM + c] = sum;
}

// h2 = relu(mean @ W2 + b2), 0 for isolated nodes
__global__ __launch_bounds__(256) void k_node_mean_relu(
    const float* __restrict__ S, const unsigned* __restrict__ cnt,
    const float* __restrict__ W, const float* __restrict__ b,
    float* __restrict__ h2) {
  __shared__ float s_m[16 * HDIM];
  __shared__ float s_scale[16];
  __shared__ float s_alive[16];
  const int tid = threadIdx.x;
  const int nb = blockIdx.x * 16;
  if (tid < 16) {
    const unsigned c = cnt[nb + tid];
    s_scale[tid] = c ? 1.f / (float)c : 0.f;
    s_alive[tid] = c ? 1.f : 0.f;
  }
  __syncthreads();
  {
    const float4* Sv = (const float4*)(S + (size_t)nb * HDIM);
    float4* mv = (float4*)s_m;
    #pragma unroll
    for (int j = 0; j < 2; ++j) {
      const int i = tid + j * 256;
      float4 v = Sv[i];
      const float sc = s_scale[i >> 5];
      v.x *= sc; v.y *= sc; v.z *= sc; v.w *= sc;
      mv[i] = v;
    }
  }
  __syncthreads();
  const int h = tid & 127;
  const int half = tid >> 7;
  float acc[8];
  #pragma unroll
  for (int j = 0; j < 8; ++j) acc[j] = 0.f;
  #pragma unroll 4
  for (int f = 0; f < HDIM; ++f) {
    const float w = W[f * HDIM + h];
    #pragma unroll
    for (int j = 0; j < 8; ++j)
      acc[j] = fmaf(s_m[(half * 8 + j) * HDIM + f], w, acc[j]);
  }
  const float bias = b[h];
  #pragma unroll
  for (int j = 0; j < 8; ++j) {
    const int n = half * 8 + j;
    h2[(size_t)(nb + n) * HDIM + h] = fmaxf(acc[j] + bias, 0.f) * s_alive[n];
  }
}

// ---------------- final: out = (mean2 @ Wfold) + bfold ; isolated -> bf -----
__global__ __launch_bounds__(256) void k_final(const float* __restrict__ S2,
                                               const unsigned* __restrict__ cnt,
                                               const float* __restrict__ Wfold,
                                               const float* __restrict__ bfold,
                                               const float* __restrict__ bf,
                                               float* __restrict__ out) {
  const int n = blockIdx.x * 256 + threadIdx.x;
  if (n >= NNODES) return;
  const unsigned c = cnt[n];
  float4 o;
  if (c == 0) {
    o.x = bf[0]; o.y = bf[1]; o.z = bf[2]; o.w = bf[3];
  } else {
    const float inv = 1.f / (float)c;
    float a0 = 0.f, a1 = 0.f, a2 = 0.f, a3 = 0.f;
    const float4* row = (const float4*)(S2 + (size_t)n * HDIM);
    const float4* Wv = (const float4*)Wfold;
    #pragma unroll 4
    for (int fq = 0; fq < 32; ++fq) {
      const float4 s4 = row[fq];
      const float vs[4] = {s4.x, s4.y, s4.z, s4.w};
      #pragma unroll
      for (int i = 0; i < 4; ++i) {
        const float v = vs[i] * inv;
        const float4 wf = Wv[fq * 4 + i];
        a0 = fmaf(v, wf.x, a0);
        a1 = fmaf(v, wf.y, a1);
        a2 = fmaf(v, wf.z, a2);
        a3 = fmaf(v, wf.w, a3);
      }
    }
    o.x = a0 + bfold[0]; o.y = a1 + bfold[1];
    o.z = a2 + bfold[2]; o.w = a3 + bfold[3];
  }
  ((float4*)out)[n] = o;
}

// ----------------------------------------------------------------------------
extern "C" void kernel_launch(void* const* d_in, const int* in_sizes, int n_in,
                              void* d_out, int out_size, void* d_ws, size_t ws_size,
                              hipStream_t stream) {
  const float* x   = (const float*)d_in[0];
  // d_in[1] = edge_attr: unused in math
  const int*   eidx = (const int*)d_in[2];
  const float* W01 = (const float*)d_in[3];
  const float* b01 = (const float*)d_in[4];
  const float* W02 = (const float*)d_in[5];
  const float* b02 = (const float*)d_in[6];
  const float* W11 = (const float*)d_in[7];
  const float* b11 = (const float*)d_in[8];
  const float* W12 = (const float*)d_in[9];
  const float* b12 = (const float*)d_in[10];
  const float* W21 = (const float*)d_in[11];
  const float* b21 = (const float*)d_in[12];
  const float* W22 = (const float*)d_in[13];
  const float* b22 = (const float*)d_in[14];
  const float* Wf  = (const float*)d_in[15];
  const float* bf  = (const float*)d_in[16];
  float* out = (float*)d_out;
  char* ws = (char*)d_ws;

  float* buf0 = (float*)(ws + OFF_BUF0);
  float* buf1 = (float*)(ws + OFF_BUF1);
  float* buf2 = (float*)(ws + OFF_BUF2);
  unsigned* cnt    = (unsigned*)(ws + OFF_CNT);
  unsigned* cursor = (unsigned*)(ws + OFF_CUR);
  unsigned* csum   = (unsigned*)(ws + OFF_CSUM);
  unsigned* coff   = (unsigned*)(ws + OFF_COFF);
  float* Wfold = (float*)(ws + OFF_WFOLD);
  float* bfold = (float*)(ws + OFF_BFOLD);
  int* flag  = (int*)(ws + OFF_FLAG);
  int* ssrc  = (int*)(ws + OFF_SSRC);
  int* sdst  = (int*)(ws + OFF_SDST);
  ushort* Whi = (ushort*)(ws + OFF_WHI);
  ushort* Wlo = (ushort*)(ws + OFF_WLO);

  // ---- counting sort of edges by dst (CSR) ----
  k_detect<<<1, 64, 0, stream>>>(eidx, flag);
  hipMemsetAsync(cnt, 0, NPAD * sizeof(unsigned), stream);
  k_count<<<NEDGES / 256, 256, 0, stream>>>(eidx, flag, cnt);
  k_scan1<<<NCH, 256, 0, stream>>>(cnt, csum);
  k_scan2<<<1, 64, 0, stream>>>(csum, coff);
  k_scan3<<<NCH, 256, 0, stream>>>(cnt, coff, cursor);
  k_scatter<<<NEDGES / 256, 256, 0, stream>>>(eidx, flag, cursor, ssrc, sdst);
  // after scatter: cursor[n] == segment end offset of node n
  k_fold<<<1, 512, 0, stream>>>(W22, Wf, b22, bf, Wfold, bfold);
  k_prepw<<<8, 256, 0, stream>>>(W02, Whi, Wlo);

  // ---- layer 0 (max aggr) ----
  k_node_ab16<<<NNODES / 16, 256, 0, stream>>>(x, W01, b01, buf0, buf1);
  hipMemsetAsync(buf2, 0, NHB, stream);
  k_edge_l0_mfma<<<NEDGES / 64, 256, 0, stream>>>(buf0, buf1, ssrc, sdst,
                                                  Whi, Wlo, b02, (unsigned*)buf2);
  k_decode<<<(int)(NH / 256), 256, 0, stream>>>((unsigned*)buf2);  // h1 = buf2

  // ---- layer 1 (mean aggr) ----
  k_node_ab<<<NNODES / 16, 256, 0, stream>>>(buf2, W11, b11, buf0, buf1);
  k_seg_mean<<<NNODES / 2, 256, 0, stream>>>(buf0, buf1, ssrc, cursor, cnt, buf2);
  k_node_mean_relu<<<NNODES / 16, 256, 0, stream>>>(buf2, cnt, W12, b12, buf0);  // h2

  // ---- layer 2 (mean aggr) + final fc ----
  k_node_ab<<<NNODES / 16, 256, 0, stream>>>(buf0, W21, b21, buf1, buf2);
  k_seg_mean<<<NNODES / 2, 256, 0, stream>>>(buf1, buf2, ssrc, cursor, cnt, buf0);
  k_final<<<(NNODES + 255) / 256, 256, 0, stream>>>(buf0, cnt, Wfold, bfold, bf, out);

  (void)in_sizes; (void)n_in; (void)out_size; (void)ws_size;
}

// Round 4
// 535.181 us; speedup vs baseline: 5.9853x; 1.1890x over previous
//
#include <hip/hip_runtime.h>
#include <stdint.h>

#define NNODES 50000
#define NEDGES 800000
#define FDIM 16
#define HDIM 128
#define NPAD 50176            // 98 * 512, padded node count for the scan
#define NCH 98                // scan chunks of 512
#define NBLK64 782            // ceil(NNODES/64)

typedef __attribute__((ext_vector_type(8))) short short8;
typedef __attribute__((ext_vector_type(4))) float f32x4;

static constexpr size_t NH  = (size_t)NNODES * HDIM;   // 6.4e6 elems
static constexpr size_t NHB = NH * sizeof(float);      // 25.6 MB

// workspace layout (16B aligned)
static constexpr size_t OFF_BUF0  = 0;
static constexpr size_t OFF_BUF1  = NHB;
static constexpr size_t OFF_BUF2  = 2 * NHB;
static constexpr size_t OFF_CNT   = 3 * NHB;                  // NPAD x u32
static constexpr size_t OFF_CUR   = OFF_CNT + NPAD * 4;       // NPAD x u32 (end offsets)
static constexpr size_t OFF_CSUM  = OFF_CUR + NPAD * 4;       // NCH x u32 (pad 512)
static constexpr size_t OFF_COFF  = OFF_CSUM + 512;           // NCH x u32
static constexpr size_t OFF_WFOLD = OFF_COFF + 512;           // 128*4 f32
static constexpr size_t OFF_BFOLD = OFF_WFOLD + 2048;         // 4 f32
static constexpr size_t OFF_FLAG  = OFF_BFOLD + 256;          // 1 int
static constexpr size_t OFF_SSRC  = OFF_FLAG + 256;           // E x i32 (sorted by dst)
static constexpr size_t OFF_SDST  = OFF_SSRC + (size_t)NEDGES * 4;
static constexpr size_t OFF_W02H  = OFF_SDST + (size_t)NEDGES * 4;  // 2048 units x 16B
static constexpr size_t OFF_W02L  = OFF_W02H + 32768;
static constexpr size_t OFF_W12H  = OFF_W02L + 32768;               // 2048 units
static constexpr size_t OFF_W12L  = OFF_W12H + 32768;
static constexpr size_t OFF_W11H  = OFF_W12L + 32768;               // 4096 units
static constexpr size_t OFF_W11L  = OFF_W11H + 65536;
static constexpr size_t OFF_W21H  = OFF_W11L + 65536;
static constexpr size_t OFF_W21L  = OFF_W21H + 65536;

__device__ inline unsigned enc_f32(float m) {
  unsigned u = __float_as_uint(m);
  return (u & 0x80000000u) ? ~u : (u | 0x80000000u);  // monotone encoding, enc>0 always
}

// rne split of fp32 into bf16 hi + bf16 lo
__device__ inline void bf16_split(float v, ushort& h, ushort& l) {
  unsigned u = __float_as_uint(v);
  unsigned hb = (u + 0x7fffu + ((u >> 16) & 1u)) & 0xffff0000u;
  h = (ushort)(hb >> 16);
  float r = v - __uint_as_float(hb);
  unsigned ur = __float_as_uint(r);
  l = (ushort)((ur + 0x7fffu + ((ur >> 16) & 1u)) >> 16);
}

// ---------------- edge-index dtype detect (int64 vs int32) ------------------
__global__ void k_detect(const int* __restrict__ raw, int* __restrict__ flag) {
  if (threadIdx.x == 0 && blockIdx.x == 0) {
    int is64 = 1;
    #pragma unroll
    for (int k = 1; k < 64; k += 2)
      if (raw[k] != 0) is64 = 0;   // int64 => high dwords zero
    *flag = is64;
  }
}

__global__ __launch_bounds__(256) void k_count(const int* __restrict__ raw,
                                               const int* __restrict__ flag,
                                               unsigned* __restrict__ cnt) {
  const size_t e = (size_t)blockIdx.x * 256 + threadIdx.x;
  const int d = (*flag) ? raw[2 * ((size_t)NEDGES + e)] : raw[NEDGES + e];
  atomicAdd(&cnt[d], 1u);
}

// ---------------- prefix scan over cnt -> cursor (exclusive offsets) --------
__global__ __launch_bounds__(256) void k_scan1(const unsigned* __restrict__ cnt,
                                               unsigned* __restrict__ csum) {
  __shared__ unsigned s[256];
  const int t = threadIdx.x, b = blockIdx.x;
  s[t] = cnt[b * 512 + t] + cnt[b * 512 + 256 + t];
  __syncthreads();
  for (int off = 128; off; off >>= 1) {
    if (t < off) s[t] += s[t + off];
    __syncthreads();
  }
  if (t == 0) csum[b] = s[0];
}

__global__ void k_scan2(const unsigned* __restrict__ csum,
                        unsigned* __restrict__ coff) {
  if (threadIdx.x == 0) {
    unsigned r = 0;
    for (int i = 0; i < NCH; ++i) { coff[i] = r; r += csum[i]; }
  }
}

__global__ __launch_bounds__(256) void k_scan3(const unsigned* __restrict__ cnt,
                                               const unsigned* __restrict__ coff,
                                               unsigned* __restrict__ cursor) {
  __shared__ unsigned s[256];
  const int t = threadIdx.x, b = blockIdx.x;
  const int base = b * 512;
  const unsigned c0 = cnt[base + 2 * t], c1 = cnt[base + 2 * t + 1];
  s[t] = c0 + c1;
  __syncthreads();
  for (int off = 1; off < 256; off <<= 1) {
    unsigned v = s[t];
    if (t >= off) v += s[t - off];
    __syncthreads();
    s[t] = v;
    __syncthreads();
  }
  const unsigned o = coff[b] + s[t] - (c0 + c1);  // exclusive pair prefix
  cursor[base + 2 * t] = o;
  cursor[base + 2 * t + 1] = o + c0;
}

__global__ __launch_bounds__(256) void k_scatter(const int* __restrict__ raw,
                                                 const int* __restrict__ flag,
                                                 unsigned* __restrict__ cursor,
                                                 int* __restrict__ ssrc,
                                                 int* __restrict__ sdst) {
  const size_t e = (size_t)blockIdx.x * 256 + threadIdx.x;
  int s, d;
  if (*flag) { s = raw[2 * e]; d = raw[2 * ((size_t)NEDGES + e)]; }
  else       { s = raw[e];     d = raw[NEDGES + e]; }
  const unsigned p = atomicAdd(&cursor[d], 1u);  // cursor ends at segment END
  ssrc[p] = s;
  sdst[p] = d;
}

// ---------------- fold W22 @ Wf (128x4) and b22 @ Wf + bf -------------------
__global__ __launch_bounds__(512) void k_fold(const float* __restrict__ W22,
                                              const float* __restrict__ Wf,
                                              const float* __restrict__ b22,
                                              const float* __restrict__ bf,
                                              float* __restrict__ Wfold,
                                              float* __restrict__ bfold) {
  const int tid = threadIdx.x;       // 512 = 128 f x 4 o
  const int f = tid >> 2, o = tid & 3;
  float acc = 0.f;
  for (int h = 0; h < HDIM; ++h)
    acc = fmaf(W22[f * HDIM + h], Wf[h * 4 + o], acc);
  Wfold[tid] = acc;
  if (tid < 4) {
    float a = bf[tid];
    for (int h = 0; h < HDIM; ++h) a = fmaf(b22[h], Wf[h * 4 + tid], a);
    bfold[tid] = a;
  }
}

// ---------------- W pack: [128][NC] fp32 -> bf16 hi/lo MFMA B-frag units ----
// unit(ct,ks,kg,row) = ((ct*4+ks)*4+kg)*16+row ; holds Wt[col=ct*16+row][k0..k0+7],
// k0 = ks*32+kg*8. Straight pack (W2-style, NC=128): 2048 units, grid 8x256.
__global__ __launch_bounds__(256) void k_prepw(const float* __restrict__ W2,
                                               ushort* __restrict__ Whi,
                                               ushort* __restrict__ Wlo) {
  const int gid = blockIdx.x * 256 + threadIdx.x;   // 0..2047
  const int row = gid & 15;
  const int kg  = (gid >> 4) & 3;
  const int ks  = (gid >> 6) & 3;
  const int ct  = gid >> 8;
  const int col = ct * 16 + row;
  const int k0  = ks * 32 + kg * 8;
  short8 hv, lv;
  #pragma unroll
  for (int j = 0; j < 8; ++j) {
    ushort h, l;
    bf16_split(W2[(size_t)(k0 + j) * HDIM + col], h, l);
    hv[j] = (short)h; lv[j] = (short)l;
  }
  *(short8*)(Whi + (size_t)gid * 8) = hv;
  *(short8*)(Wlo + (size_t)gid * 8) = lv;
}

// AB pack: W1 is [256][128]; Wcat[k][col] = col<128 ? W1[k][col]-W1[k+128][col]
//                                         : W1[k+128][col-128]. 4096 units, 16x256.
__global__ __launch_bounds__(256) void k_packw_ab(const float* __restrict__ W1,
                                                  ushort* __restrict__ Whi,
                                                  ushort* __restrict__ Wlo) {
  const int gid = blockIdx.x * 256 + threadIdx.x;   // 0..4095
  const int row = gid & 15;
  const int kg  = (gid >> 4) & 3;
  const int ks  = (gid >> 6) & 3;
  const int ct  = gid >> 8;                          // 0..15
  const int col = ct * 16 + row;
  const int k0  = ks * 32 + kg * 8;
  short8 hv, lv;
  #pragma unroll
  for (int j = 0; j < 8; ++j) {
    const int k = k0 + j;
    float v;
    if (col < HDIM) v = W1[(size_t)k * HDIM + col] - W1[(size_t)(k + HDIM) * HDIM + col];
    else            v = W1[(size_t)(k + HDIM) * HDIM + (col - HDIM)];
    ushort h, l;
    bf16_split(v, h, l);
    hv[j] = (short)h; lv[j] = (short)l;
  }
  *(short8*)(Whi + (size_t)gid * 8) = hv;
  *(short8*)(Wlo + (size_t)gid * 8) = lv;
}

// ---------------- layer-0 node projection (K=16), VALU ----------------------
__global__ __launch_bounds__(256) void k_node_ab16(const float* __restrict__ x,
                                                   const float* __restrict__ W1,
                                                   const float* __restrict__ b1,
                                                   float* __restrict__ A,
                                                   float* __restrict__ B) {
  __shared__ float s_x[16 * FDIM];
  const int tid = threadIdx.x;
  const int nb = blockIdx.x * 16;
  s_x[tid] = x[(size_t)nb * FDIM + tid];
  __syncthreads();
  const int h = tid & 127;
  const int half = tid >> 7;
  float accA[8], accB[8];
  #pragma unroll
  for (int j = 0; j < 8; ++j) { accA[j] = 0.f; accB[j] = 0.f; }
  #pragma unroll 4
  for (int f = 0; f < FDIM; ++f) {
    const float wt = W1[f * HDIM + h];
    const float wb = W1[(f + FDIM) * HDIM + h];
    const float wd = wt - wb;
    #pragma unroll
    for (int j = 0; j < 8; ++j) {
      const float xv = s_x[(half * 8 + j) * FDIM + f];
      accA[j] = fmaf(xv, wd, accA[j]);
      accB[j] = fmaf(xv, wb, accB[j]);
    }
  }
  const float bias = b1[h];
  #pragma unroll
  for (int j = 0; j < 8; ++j) {
    const size_t idx = (size_t)(nb + half * 8 + j) * HDIM + h;
    A[idx] = accA[j] + bias;
    B[idx] = accB[j];
  }
}

// ---------------- node A|B projection via split-bf16 MFMA -------------------
// C[64 x 256] = X[64 x 128] @ Wcat ; cols 0-127 -> A (+b1), 128-255 -> B.
// DECODE=1: input is monotone-encoded uint (layer-0 max output), decode inline.
template <int DECODE>
__global__ __launch_bounds__(256) void k_node_ab_mfma(
    const float* __restrict__ X, const ushort* __restrict__ Whi,
    const ushort* __restrict__ Wlo, const float* __restrict__ b1,
    float* __restrict__ A, float* __restrict__ B) {
  __shared__ __align__(16) ushort s_hi[64 * 128];
  __shared__ __align__(16) ushort s_lo[64 * 128];
  const int tid = threadIdx.x;
  const int nb = blockIdx.x * 64;

  #pragma unroll
  for (int it = 0; it < 4; ++it) {
    const int idx = tid + it * 256;
    const int row = idx >> 4;
    const int kg8 = idx & 15;
    const int n = nb + row;
    float v[8];
    if (n < NNODES) {
      if (DECODE) {
        const unsigned* p = (const unsigned*)X + (size_t)n * HDIM + kg8 * 8;
        const uint4 u0 = *(const uint4*)p;
        const uint4 u1 = *(const uint4*)(p + 4);
        const unsigned uu[8] = {u0.x, u0.y, u0.z, u0.w, u1.x, u1.y, u1.z, u1.w};
        #pragma unroll
        for (int j = 0; j < 8; ++j)
          v[j] = (uu[j] & 0x80000000u) ? __uint_as_float(uu[j] ^ 0x80000000u) : 0.f;
      } else {
        const float* p = X + (size_t)n * HDIM + kg8 * 8;
        const float4 a0 = *(const float4*)p;
        const float4 a1 = *(const float4*)(p + 4);
        v[0] = a0.x; v[1] = a0.y; v[2] = a0.z; v[3] = a0.w;
        v[4] = a1.x; v[5] = a1.y; v[6] = a1.z; v[7] = a1.w;
      }
    } else {
      #pragma unroll
      for (int j = 0; j < 8; ++j) v[j] = 0.f;
    }
    short8 hv, lv;
    #pragma unroll
    for (int j = 0; j < 8; ++j) {
      ushort h, l;
      bf16_split(v[j], h, l);
      hv[j] = (short)h; lv[j] = (short)l;
    }
    const int unit = row * 16 + (kg8 ^ (row & 15));
    *(short8*)(s_hi + unit * 8) = hv;
    *(short8*)(s_lo + unit * 8) = lv;
  }
  __syncthreads();

  const int l15 = tid & 15;
  const int l4  = (tid >> 4) & 3;
  const int w   = tid >> 6;

  f32x4 acc[4][4];
  #pragma unroll
  for (int rt = 0; rt < 4; ++rt)
    #pragma unroll
    for (int c = 0; c < 4; ++c)
      #pragma unroll
      for (int r = 0; r < 4; ++r) acc[rt][c][r] = 0.f;

  #pragma unroll
  for (int ks = 0; ks < 4; ++ks) {
    short8 wh[4], wl[4];
    #pragma unroll
    for (int ctl = 0; ctl < 4; ++ctl) {
      const int ct_g = w * 4 + ctl;
      const size_t u = ((size_t)(((ct_g * 4 + ks) * 4 + l4) * 16 + l15)) * 8;
      wh[ctl] = *(const short8*)(Whi + u);
      wl[ctl] = *(const short8*)(Wlo + u);
    }
    #pragma unroll
    for (int rt = 0; rt < 4; ++rt) {
      const int unit = (rt * 16 + l15) * 16 + ((ks * 4 + l4) ^ l15);
      const short8 ah = *(const short8*)(s_hi + unit * 8);
      const short8 al = *(const short8*)(s_lo + unit * 8);
      #pragma unroll
      for (int ctl = 0; ctl < 4; ++ctl) {
        acc[rt][ctl] = __builtin_amdgcn_mfma_f32_16x16x32_bf16(al, wh[ctl], acc[rt][ctl], 0, 0, 0);
        acc[rt][ctl] = __builtin_amdgcn_mfma_f32_16x16x32_bf16(ah, wl[ctl], acc[rt][ctl], 0, 0, 0);
        acc[rt][ctl] = __builtin_amdgcn_mfma_f32_16x16x32_bf16(ah, wh[ctl], acc[rt][ctl], 0, 0, 0);
      }
    }
  }

  #pragma unroll
  for (int ctl = 0; ctl < 4; ++ctl) {
    const int col_g = w * 64 + ctl * 16 + l15;
    const bool isA = col_g < HDIM;           // uniform per (w,ctl)
    const float bias = isA ? b1[col_g] : 0.f;
    float* const base = isA ? (A + col_g) : (B + col_g - HDIM);
    #pragma unroll
    for (int rt = 0; rt < 4; ++rt)
      #pragma unroll
      for (int r = 0; r < 4; ++r) {
        const int n = nb + rt * 16 + l4 * 4 + r;
        if (n < NNODES) base[(size_t)n * HDIM] = acc[rt][ctl][r] + bias;
      }
  }
}

// ---------------- node mean+GEMM+relu via split-bf16 MFMA -------------------
// h2[64 x 128] = relu((S*scale) @ W2 + b2) * alive
__global__ __launch_bounds__(256) void k_node_mr_mfma(
    const float* __restrict__ S, const unsigned* __restrict__ cnt,
    const ushort* __restrict__ Whi, const ushort* __restrict__ Wlo,
    const float* __restrict__ b, float* __restrict__ h2) {
  __shared__ __align__(16) ushort s_hi[64 * 128];
  __shared__ __align__(16) ushort s_lo[64 * 128];
  __shared__ float s_scale[64];
  __shared__ float s_alive[64];
  const int tid = threadIdx.x;
  const int nb = blockIdx.x * 64;
  if (tid < 64) {
    const int n = nb + tid;
    const unsigned c = (n < NNODES) ? cnt[n] : 0u;
    s_scale[tid] = c ? 1.f / (float)c : 0.f;
    s_alive[tid] = c ? 1.f : 0.f;
  }
  __syncthreads();

  #pragma unroll
  for (int it = 0; it < 4; ++it) {
    const int idx = tid + it * 256;
    const int row = idx >> 4;
    const int kg8 = idx & 15;
    const int n = nb + row;
    float v[8];
    if (n < NNODES) {
      const float sc = s_scale[row];
      const float* p = S + (size_t)n * HDIM + kg8 * 8;
      const float4 a0 = *(const float4*)p;
      const float4 a1 = *(const float4*)(p + 4);
      v[0] = a0.x * sc; v[1] = a0.y * sc; v[2] = a0.z * sc; v[3] = a0.w * sc;
      v[4] = a1.x * sc; v[5] = a1.y * sc; v[6] = a1.z * sc; v[7] = a1.w * sc;
    } else {
      #pragma unroll
      for (int j = 0; j < 8; ++j) v[j] = 0.f;
    }
    short8 hv, lv;
    #pragma unroll
    for (int j = 0; j < 8; ++j) {
      ushort h, l;
      bf16_split(v[j], h, l);
      hv[j] = (short)h; lv[j] = (short)l;
    }
    const int unit = row * 16 + (kg8 ^ (row & 15));
    *(short8*)(s_hi + unit * 8) = hv;
    *(short8*)(s_lo + unit * 8) = lv;
  }
  __syncthreads();

  const int l15 = tid & 15;
  const int l4  = (tid >> 4) & 3;
  const int w   = tid >> 6;

  f32x4 acc[4][2];
  #pragma unroll
  for (int rt = 0; rt < 4; ++rt)
    #pragma unroll
    for (int c = 0; c < 2; ++c)
      #pragma unroll
      for (int r = 0; r < 4; ++r) acc[rt][c][r] = 0.f;

  #pragma unroll
  for (int ks = 0; ks < 4; ++ks) {
    short8 wh[2], wl[2];
    #pragma unroll
    for (int ctl = 0; ctl < 2; ++ctl) {
      const int ct_g = w * 2 + ctl;
      const size_t u = ((size_t)(((ct_g * 4 + ks) * 4 + l4) * 16 + l15)) * 8;
      wh[ctl] = *(const short8*)(Whi + u);
      wl[ctl] = *(const short8*)(Wlo + u);
    }
    #pragma unroll
    for (int rt = 0; rt < 4; ++rt) {
      const int unit = (rt * 16 + l15) * 16 + ((ks * 4 + l4) ^ l15);
      const short8 ah = *(const short8*)(s_hi + unit * 8);
      const short8 al = *(const short8*)(s_lo + unit * 8);
      #pragma unroll
      for (int ctl = 0; ctl < 2; ++ctl) {
        acc[rt][ctl] = __builtin_amdgcn_mfma_f32_16x16x32_bf16(al, wh[ctl], acc[rt][ctl], 0, 0, 0);
        acc[rt][ctl] = __builtin_amdgcn_mfma_f32_16x16x32_bf16(ah, wl[ctl], acc[rt][ctl], 0, 0, 0);
        acc[rt][ctl] = __builtin_amdgcn_mfma_f32_16x16x32_bf16(ah, wh[ctl], acc[rt][ctl], 0, 0, 0);
      }
    }
  }

  #pragma unroll
  for (int ctl = 0; ctl < 2; ++ctl) {
    const int col_g = w * 32 + ctl * 16 + l15;
    const float bias = b[col_g];
    #pragma unroll
    for (int rt = 0; rt < 4; ++rt)
      #pragma unroll
      for (int r = 0; r < 4; ++r) {
        const int row = rt * 16 + l4 * 4 + r;
        const int n = nb + row;
        if (n < NNODES)
          h2[(size_t)n * HDIM + col_g] = fmaxf(acc[rt][ctl][r] + bias, 0.f) * s_alive[row];
      }
  }
}

// ---------------- layer 0: split-bf16 MFMA edge GEMM + LDS segmented max ----
__global__ __launch_bounds__(256) void k_edge_l0_mfma(
    const float* __restrict__ A0, const float* __restrict__ B0,
    const int* __restrict__ ssrc, const int* __restrict__ sdst,
    const ushort* __restrict__ Whi, const ushort* __restrict__ Wlo,
    const float* __restrict__ b2, unsigned* __restrict__ outenc) {
  __shared__ __align__(16) char s_un[4 * 64 * 33 * 4];
  __shared__ int s_dstA[64];
  __shared__ int s_srcA[64];
  ushort* s_thi = (ushort*)s_un;
  ushort* s_tlo = (ushort*)(s_un + 16384);
  float*  s_m   = (float*)s_un;

  const int tid = threadIdx.x;
  const int eb = blockIdx.x * 64;
  if (tid < 64) s_dstA[tid] = sdst[eb + tid];
  else if (tid < 128) s_srcA[tid - 64] = ssrc[eb + tid - 64];
  __syncthreads();

  #pragma unroll
  for (int it = 0; it < 4; ++it) {
    const int idx = tid + it * 256;
    const int e = idx >> 4;
    const int kg8 = idx & 15;
    const int k0 = kg8 * 8;
    const float* ap = A0 + (size_t)s_dstA[e] * HDIM + k0;
    const float* bp = B0 + (size_t)s_srcA[e] * HDIM + k0;
    const float4 a0 = *(const float4*)ap;
    const float4 a1 = *(const float4*)(ap + 4);
    const float4 b0 = *(const float4*)bp;
    const float4 b1 = *(const float4*)(bp + 4);
    float v[8] = {a0.x + b0.x, a0.y + b0.y, a0.z + b0.z, a0.w + b0.w,
                  a1.x + b1.x, a1.y + b1.y, a1.z + b1.z, a1.w + b1.w};
    short8 hv, lv;
    #pragma unroll
    for (int j = 0; j < 8; ++j) {
      const float vv = fmaxf(v[j], 0.f);
      ushort h, l;
      bf16_split(vv, h, l);
      hv[j] = (short)h; lv[j] = (short)l;
    }
    const int unit = e * 16 + (kg8 ^ (e & 15));
    *(short8*)(s_thi + unit * 8) = hv;
    *(short8*)(s_tlo + unit * 8) = lv;
  }
  __syncthreads();

  const int l15 = tid & 15;
  const int l4  = (tid >> 4) & 3;
  const int w   = tid >> 6;

  f32x4 acc[4][2];
  #pragma unroll
  for (int rt = 0; rt < 4; ++rt)
    #pragma unroll
    for (int c = 0; c < 2; ++c)
      #pragma unroll
      for (int r = 0; r < 4; ++r) acc[rt][c][r] = 0.f;

  #pragma unroll
  for (int ks = 0; ks < 4; ++ks) {
    short8 wh[2], wl[2];
    #pragma unroll
    for (int ctl = 0; ctl < 2; ++ctl) {
      const int ct_g = w * 2 + ctl;
      const size_t u = ((size_t)(((ct_g * 4 + ks) * 4 + l4) * 16 + l15)) * 8;
      wh[ctl] = *(const short8*)(Whi + u);
      wl[ctl] = *(const short8*)(Wlo + u);
    }
    #pragma unroll
    for (int rt = 0; rt < 4; ++rt) {
      const int e = rt * 16 + l15;
      const int unit = e * 16 + ((ks * 4 + l4) ^ l15);
      const short8 ah = *(const short8*)(s_thi + unit * 8);
      const short8 al = *(const short8*)(s_tlo + unit * 8);
      #pragma unroll
      for (int ctl = 0; ctl < 2; ++ctl) {
        acc[rt][ctl] = __builtin_amdgcn_mfma_f32_16x16x32_bf16(al, wh[ctl], acc[rt][ctl], 0, 0, 0);
        acc[rt][ctl] = __builtin_amdgcn_mfma_f32_16x16x32_bf16(ah, wl[ctl], acc[rt][ctl], 0, 0, 0);
        acc[rt][ctl] = __builtin_amdgcn_mfma_f32_16x16x32_bf16(ah, wh[ctl], acc[rt][ctl], 0, 0, 0);
      }
    }
  }
  __syncthreads();

  const float bb0 = b2[w * 32 + l15];
  const float bb1 = b2[w * 32 + 16 + l15];
  float* sm = s_m + w * (64 * 33);
  #pragma unroll
  for (int rt = 0; rt < 4; ++rt)
    #pragma unroll
    for (int ctl = 0; ctl < 2; ++ctl)
      #pragma unroll
      for (int r = 0; r < 4; ++r)
        sm[(rt * 16 + l4 * 4 + r) * 33 + ctl * 16 + l15] =
            acc[rt][ctl][r] + (ctl ? bb1 : bb0);
  __syncthreads();

  {
    const int l = tid & 63;
    const int col = l & 31;
    const int g = l >> 5;
    const int e0 = g * 32;
    int curd = s_dstA[e0];
    float run = sm[e0 * 33 + col];
    for (int e = e0 + 1; e < e0 + 32; ++e) {
      const int d = s_dstA[e];
      const float v = sm[e * 33 + col];
      if (d == curd) run = fmaxf(run, v);
      else {
        atomicMax(outenc + (size_t)curd * HDIM + w * 32 + col, enc_f32(run));
        curd = d; run = v;
      }
    }
    atomicMax(outenc + (size_t)curd * HDIM + w * 32 + col, enc_f32(run));
  }
}

// ---------------- mean layers: wave-per-node CSR sum, float2/lane -----------
__global__ __launch_bounds__(256) void k_seg_mean(const float* __restrict__ A,
                                                  const float* __restrict__ B,
                                                  const int* __restrict__ ssrc,
                                                  const unsigned* __restrict__ endv,
                                                  const unsigned* __restrict__ cnt,
                                                  float* __restrict__ S) {
  const int tid = threadIdx.x;
  const int n = blockIdx.x * 4 + (tid >> 6);
  const int lane = tid & 63;
  const unsigned end = endv[n];
  unsigned e = end - cnt[n];
  const float2 a = *(const float2*)(A + (size_t)n * HDIM + lane * 2);
  float sx = 0.f, sy = 0.f;
  for (; e + 8 <= end; e += 8) {
    int s[8];
    #pragma unroll
    for (int k = 0; k < 8; ++k) s[k] = ssrc[e + k];
    float2 v[8];
    #pragma unroll
    for (int k = 0; k < 8; ++k)
      v[k] = *(const float2*)(B + (size_t)s[k] * HDIM + lane * 2);
    #pragma unroll
    for (int k = 0; k < 8; ++k) {
      sx += fmaxf(a.x + v[k].x, 0.f);
      sy += fmaxf(a.y + v[k].y, 0.f);
    }
  }
  for (; e + 2 <= end; e += 2) {
    const int s0 = ssrc[e], s1 = ssrc[e + 1];
    const float2 v0 = *(const float2*)(B + (size_t)s0 * HDIM + lane * 2);
    const float2 v1 = *(const float2*)(B + (size_t)s1 * HDIM + lane * 2);
    sx += fmaxf(a.x + v0.x, 0.f) + fmaxf(a.x + v1.x, 0.f);
    sy += fmaxf(a.y + v0.y, 0.f) + fmaxf(a.y + v1.y, 0.f);
  }
  for (; e < end; ++e) {
    const float2 v = *(const float2*)(B + (size_t)ssrc[e] * HDIM + lane * 2);
    sx += fmaxf(a.x + v.x, 0.f);
    sy += fmaxf(a.y + v.y, 0.f);
  }
  float2 o; o.x = sx; o.y = sy;
  *(float2*)(S + (size_t)n * HDIM + lane * 2) = o;
}

// ---------------- final: out = (mean2 @ Wfold) + bfold ; isolated -> bf -----
__global__ __launch_bounds__(256) void k_final(const float* __restrict__ S2,
                                               const unsigned* __restrict__ cnt,
                                               const float* __restrict__ Wfold,
                                               const float* __restrict__ bfold,
                                               const float* __restrict__ bf,
                                               float* __restrict__ out) {
  const int n = blockIdx.x * 256 + threadIdx.x;
  if (n >= NNODES) return;
  const unsigned c = cnt[n];
  float4 o;
  if (c == 0) {
    o.x = bf[0]; o.y = bf[1]; o.z = bf[2]; o.w = bf[3];
  } else {
    const float inv = 1.f / (float)c;
    float a0 = 0.f, a1 = 0.f, a2 = 0.f, a3 = 0.f;
    const float4* row = (const float4*)(S2 + (size_t)n * HDIM);
    const float4* Wv = (const float4*)Wfold;
    #pragma unroll 4
    for (int fq = 0; fq < 32; ++fq) {
      const float4 s4 = row[fq];
      const float vs[4] = {s4.x, s4.y, s4.z, s4.w};
      #pragma unroll
      for (int i = 0; i < 4; ++i) {
        const float v = vs[i] * inv;
        const float4 wf = Wv[fq * 4 + i];
        a0 = fmaf(v, wf.x, a0);
        a1 = fmaf(v, wf.y, a1);
        a2 = fmaf(v, wf.z, a2);
        a3 = fmaf(v, wf.w, a3);
      }
    }
    o.x = a0 + bfold[0]; o.y = a1 + bfold[1];
    o.z = a2 + bfold[2]; o.w = a3 + bfold[3];
  }
  ((float4*)out)[n] = o;
}

// ----------------------------------------------------------------------------
extern "C" void kernel_launch(void* const* d_in, const int* in_sizes, int n_in,
                              void* d_out, int out_size, void* d_ws, size_t ws_size,
                              hipStream_t stream) {
  const float* x   = (const float*)d_in[0];
  // d_in[1] = edge_attr: unused in math
  const int*   eidx = (const int*)d_in[2];
  const float* W01 = (const float*)d_in[3];
  const float* b01 = (const float*)d_in[4];
  const float* W02 = (const float*)d_in[5];
  const float* b02 = (const float*)d_in[6];
  const float* W11 = (const float*)d_in[7];
  const float* b11 = (const float*)d_in[8];
  const float* W12 = (const float*)d_in[9];
  const float* b12 = (const float*)d_in[10];
  const float* W21 = (const float*)d_in[11];
  const float* b21 = (const float*)d_in[12];
  const float* W22 = (const float*)d_in[13];
  const float* b22 = (const float*)d_in[14];
  const float* Wf  = (const float*)d_in[15];
  const float* bf  = (const float*)d_in[16];
  float* out = (float*)d_out;
  char* ws = (char*)d_ws;

  float* buf0 = (float*)(ws + OFF_BUF0);
  float* buf1 = (float*)(ws + OFF_BUF1);
  float* buf2 = (float*)(ws + OFF_BUF2);
  unsigned* cnt    = (unsigned*)(ws + OFF_CNT);
  unsigned* cursor = (unsigned*)(ws + OFF_CUR);
  unsigned* csum   = (unsigned*)(ws + OFF_CSUM);
  unsigned* coff   = (unsigned*)(ws + OFF_COFF);
  float* Wfold = (float*)(ws + OFF_WFOLD);
  float* bfold = (float*)(ws + OFF_BFOLD);
  int* flag  = (int*)(ws + OFF_FLAG);
  int* ssrc  = (int*)(ws + OFF_SSRC);
  int* sdst  = (int*)(ws + OFF_SDST);
  ushort* W02h = (ushort*)(ws + OFF_W02H);
  ushort* W02l = (ushort*)(ws + OFF_W02L);
  ushort* W12h = (ushort*)(ws + OFF_W12H);
  ushort* W12l = (ushort*)(ws + OFF_W12L);
  ushort* W11h = (ushort*)(ws + OFF_W11H);
  ushort* W11l = (ushort*)(ws + OFF_W11L);
  ushort* W21h = (ushort*)(ws + OFF_W21H);
  ushort* W21l = (ushort*)(ws + OFF_W21L);

  // ---- counting sort of edges by dst (CSR) + weight prep ----
  k_detect<<<1, 64, 0, stream>>>(eidx, flag);
  hipMemsetAsync(cnt, 0, NPAD * sizeof(unsigned), stream);
  k_count<<<NEDGES / 256, 256, 0, stream>>>(eidx, flag, cnt);
  k_scan1<<<NCH, 256, 0, stream>>>(cnt, csum);
  k_scan2<<<1, 64, 0, stream>>>(csum, coff);
  k_scan3<<<NCH, 256, 0, stream>>>(cnt, coff, cursor);
  k_scatter<<<NEDGES / 256, 256, 0, stream>>>(eidx, flag, cursor, ssrc, sdst);
  // after scatter: cursor[n] == segment end offset of node n
  k_fold<<<1, 512, 0, stream>>>(W22, Wf, b22, bf, Wfold, bfold);
  k_prepw<<<8, 256, 0, stream>>>(W02, W02h, W02l);
  k_prepw<<<8, 256, 0, stream>>>(W12, W12h, W12l);
  k_packw_ab<<<16, 256, 0, stream>>>(W11, W11h, W11l);
  k_packw_ab<<<16, 256, 0, stream>>>(W21, W21h, W21l);

  // ---- layer 0 (max aggr) ----
  k_node_ab16<<<NNODES / 16, 256, 0, stream>>>(x, W01, b01, buf0, buf1);
  hipMemsetAsync(buf2, 0, NHB, stream);
  k_edge_l0_mfma<<<NEDGES / 64, 256, 0, stream>>>(buf0, buf1, ssrc, sdst,
                                                  W02h, W02l, b02, (unsigned*)buf2);
  // buf2 = encoded h1 (decode fused into next stage)

  // ---- layer 1 (mean aggr) ----
  k_node_ab_mfma<1><<<NBLK64, 256, 0, stream>>>(buf2, W11h, W11l, b11, buf0, buf1);
  k_seg_mean<<<NNODES / 4, 256, 0, stream>>>(buf0, buf1, ssrc, cursor, cnt, buf2);
  k_node_mr_mfma<<<NBLK64, 256, 0, stream>>>(buf2, cnt, W12h, W12l, b12, buf0);  // h2

  // ---- layer 2 (mean aggr) + final fc ----
  k_node_ab_mfma<0><<<NBLK64, 256, 0, stream>>>(buf0, W21h, W21l, b21, buf1, buf2);
  k_seg_mean<<<NNODES / 4, 256, 0, stream>>>(buf1, buf2, ssrc, cursor, cnt, buf0);
  k_final<<<(NNODES + 255) / 256, 256, 0, stream>>>(buf0, cnt, Wfold, bfold, bf, out);

  (void)in_sizes; (void)n_in; (void)out_size; (void)ws_size;
}

// Round 5
// 502.057 us; speedup vs baseline: 6.3802x; 1.0660x over previous
//
#include <hip/hip_runtime.h>
#include <stdint.h>

#define NNODES 50000
#define NEDGES 800000
#define FDIM 16
#define HDIM 128
#define NPAD 50176            // 98 * 512, padded node count for the scan
#define NCH 98                // scan chunks of 512
#define NBLK64 782            // ceil(NNODES/64)

typedef __attribute__((ext_vector_type(8))) short short8;
typedef __attribute__((ext_vector_type(4))) float f32x4;

static constexpr size_t NH  = (size_t)NNODES * HDIM;   // 6.4e6 elems
static constexpr size_t NHB = NH * sizeof(float);      // 25.6 MB

// workspace layout (16B aligned)
static constexpr size_t OFF_BUF0  = 0;
static constexpr size_t OFF_BUF1  = NHB;
static constexpr size_t OFF_BUF2  = 2 * NHB;
static constexpr size_t OFF_CNT   = 3 * NHB;                  // NPAD x u32
static constexpr size_t OFF_CUR   = OFF_CNT + NPAD * 4;       // NPAD x u32 (end offsets)
static constexpr size_t OFF_CSUM  = OFF_CUR + NPAD * 4;       // NCH x u32 (pad 512)
static constexpr size_t OFF_COFF  = OFF_CSUM + 512;           // NCH x u32
static constexpr size_t OFF_WFOLD = OFF_COFF + 512;           // 128*4 f32
static constexpr size_t OFF_BFOLD = OFF_WFOLD + 2048;         // 4 f32
static constexpr size_t OFF_FLAG  = OFF_BFOLD + 256;          // 1 int
static constexpr size_t OFF_SSRC  = OFF_FLAG + 256;           // E x i32 (sorted by dst)
static constexpr size_t OFF_SDST  = OFF_SSRC + (size_t)NEDGES * 4;
static constexpr size_t OFF_W02H  = OFF_SDST + (size_t)NEDGES * 4;  // 2048 units x 16B
static constexpr size_t OFF_W02L  = OFF_W02H + 32768;
static constexpr size_t OFF_W12H  = OFF_W02L + 32768;               // 2048 units
static constexpr size_t OFF_W12L  = OFF_W12H + 32768;
static constexpr size_t OFF_W11H  = OFF_W12L + 32768;               // 4096 units
static constexpr size_t OFF_W11L  = OFF_W11H + 65536;
static constexpr size_t OFF_W21H  = OFF_W11L + 65536;
static constexpr size_t OFF_W21L  = OFF_W21H + 65536;

__device__ inline unsigned enc_f32(float m) {
  unsigned u = __float_as_uint(m);
  return (u & 0x80000000u) ? ~u : (u | 0x80000000u);  // monotone encoding, enc>0 always
}

// rne split (weights only, prep-time)
__device__ inline void bf16_split(float v, ushort& h, ushort& l) {
  unsigned u = __float_as_uint(v);
  unsigned hb = (u + 0x7fffu + ((u >> 16) & 1u)) & 0xffff0000u;
  h = (ushort)(hb >> 16);
  float r = v - __uint_as_float(hb);
  unsigned ur = __float_as_uint(r);
  l = (ushort)((ur + 0x7fffu + ((ur >> 16) & 1u)) >> 16);
}

// cheap truncation split of 8 floats -> bf16 hi/lo fragments (pair-packed;
// hi residual is EXACT in fp32, lo trunc => t represented to 2^-16 rel)
__device__ inline void split8_tr(const float v[8], short8& hv, short8& lv) {
  unsigned hp[4], lp[4];
  #pragma unroll
  for (int k = 0; k < 4; ++k) {
    const unsigned u0 = __float_as_uint(v[2 * k]);
    const unsigned u1 = __float_as_uint(v[2 * k + 1]);
    const unsigned h0 = u0 & 0xffff0000u;
    const unsigned h1 = u1 & 0xffff0000u;
    const float r0 = v[2 * k]     - __uint_as_float(h0);
    const float r1 = v[2 * k + 1] - __uint_as_float(h1);
    hp[k] = h1 | (h0 >> 16);
    lp[k] = (__float_as_uint(r1) & 0xffff0000u) | (__float_as_uint(r0) >> 16);
  }
  hv = *(short8*)hp;
  lv = *(short8*)lp;
}

// ---------------- init: zero cnt + edge-index dtype detect ------------------
__global__ __launch_bounds__(256) void k_init(const int* __restrict__ raw,
                                              int* __restrict__ flag,
                                              unsigned* __restrict__ cnt) {
  const int i = blockIdx.x * 256 + threadIdx.x;
  cnt[i] = 0u;                       // grid covers NPAD exactly
  if (blockIdx.x == 0 && threadIdx.x == 0) {
    int is64 = 1;
    #pragma unroll
    for (int k = 1; k < 64; k += 2)
      if (raw[k] != 0) is64 = 0;     // int64 => high dwords zero
    *flag = is64;
  }
}

__global__ __launch_bounds__(256) void k_count(const int* __restrict__ raw,
                                               const int* __restrict__ flag,
                                               unsigned* __restrict__ cnt) {
  const size_t e = (size_t)blockIdx.x * 256 + threadIdx.x;
  const int d = (*flag) ? raw[2 * ((size_t)NEDGES + e)] : raw[NEDGES + e];
  atomicAdd(&cnt[d], 1u);
}

// ---------------- prefix scan over cnt -> cursor (exclusive offsets) --------
__global__ __launch_bounds__(256) void k_scan1(const unsigned* __restrict__ cnt,
                                               unsigned* __restrict__ csum) {
  __shared__ unsigned s[256];
  const int t = threadIdx.x, b = blockIdx.x;
  s[t] = cnt[b * 512 + t] + cnt[b * 512 + 256 + t];
  __syncthreads();
  for (int off = 128; off; off >>= 1) {
    if (t < off) s[t] += s[t + off];
    __syncthreads();
  }
  if (t == 0) csum[b] = s[0];
}

__global__ void k_scan2(const unsigned* __restrict__ csum,
                        unsigned* __restrict__ coff) {
  if (threadIdx.x == 0) {
    unsigned r = 0;
    for (int i = 0; i < NCH; ++i) { coff[i] = r; r += csum[i]; }
  }
}

__global__ __launch_bounds__(256) void k_scan3(const unsigned* __restrict__ cnt,
                                               const unsigned* __restrict__ coff,
                                               unsigned* __restrict__ cursor) {
  __shared__ unsigned s[256];
  const int t = threadIdx.x, b = blockIdx.x;
  const int base = b * 512;
  const unsigned c0 = cnt[base + 2 * t], c1 = cnt[base + 2 * t + 1];
  s[t] = c0 + c1;
  __syncthreads();
  for (int off = 1; off < 256; off <<= 1) {
    unsigned v = s[t];
    if (t >= off) v += s[t - off];
    __syncthreads();
    s[t] = v;
    __syncthreads();
  }
  const unsigned o = coff[b] + s[t] - (c0 + c1);  // exclusive pair prefix
  cursor[base + 2 * t] = o;
  cursor[base + 2 * t + 1] = o + c0;
}

__global__ __launch_bounds__(256) void k_scatter(const int* __restrict__ raw,
                                                 const int* __restrict__ flag,
                                                 unsigned* __restrict__ cursor,
                                                 int* __restrict__ ssrc,
                                                 int* __restrict__ sdst) {
  const size_t e = (size_t)blockIdx.x * 256 + threadIdx.x;
  int s, d;
  if (*flag) { s = raw[2 * e]; d = raw[2 * ((size_t)NEDGES + e)]; }
  else       { s = raw[e];     d = raw[NEDGES + e]; }
  const unsigned p = atomicAdd(&cursor[d], 1u);  // cursor ends at segment END
  ssrc[p] = s;
  sdst[p] = d;
}

// ---------------- all weight prep in ONE kernel -----------------------------
// blocks 0-7: pack W02 ; 8-15: pack W12 ; 16-31: packAB W11 ; 32-47: packAB W21
// blocks 48-49: fold W22@Wf + b22@Wf+bf
__device__ inline void prepw_body(const float* __restrict__ W2,
                                  ushort* __restrict__ Whi,
                                  ushort* __restrict__ Wlo, int blk) {
  const int gid = blk * 256 + threadIdx.x;   // 0..2047
  const int row = gid & 15;
  const int kg  = (gid >> 4) & 3;
  const int ks  = (gid >> 6) & 3;
  const int ct  = gid >> 8;
  const int col = ct * 16 + row;
  const int k0  = ks * 32 + kg * 8;
  short8 hv, lv;
  #pragma unroll
  for (int j = 0; j < 8; ++j) {
    ushort h, l;
    bf16_split(W2[(size_t)(k0 + j) * HDIM + col], h, l);
    hv[j] = (short)h; lv[j] = (short)l;
  }
  *(short8*)(Whi + (size_t)gid * 8) = hv;
  *(short8*)(Wlo + (size_t)gid * 8) = lv;
}

__device__ inline void packab_body(const float* __restrict__ W1,
                                   ushort* __restrict__ Whi,
                                   ushort* __restrict__ Wlo, int blk) {
  const int gid = blk * 256 + threadIdx.x;   // 0..4095
  const int row = gid & 15;
  const int kg  = (gid >> 4) & 3;
  const int ks  = (gid >> 6) & 3;
  const int ct  = gid >> 8;                   // 0..15
  const int col = ct * 16 + row;
  const int k0  = ks * 32 + kg * 8;
  short8 hv, lv;
  #pragma unroll
  for (int j = 0; j < 8; ++j) {
    const int k = k0 + j;
    float v;
    if (col < HDIM) v = W1[(size_t)k * HDIM + col] - W1[(size_t)(k + HDIM) * HDIM + col];
    else            v = W1[(size_t)(k + HDIM) * HDIM + (col - HDIM)];
    ushort h, l;
    bf16_split(v, h, l);
    hv[j] = (short)h; lv[j] = (short)l;
  }
  *(short8*)(Whi + (size_t)gid * 8) = hv;
  *(short8*)(Wlo + (size_t)gid * 8) = lv;
}

__global__ __launch_bounds__(256) void k_prep_all(
    const float* __restrict__ W02, const float* __restrict__ W12,
    const float* __restrict__ W11, const float* __restrict__ W21,
    const float* __restrict__ W22, const float* __restrict__ Wf,
    const float* __restrict__ b22, const float* __restrict__ bf,
    ushort* __restrict__ W02h, ushort* __restrict__ W02l,
    ushort* __restrict__ W12h, ushort* __restrict__ W12l,
    ushort* __restrict__ W11h, ushort* __restrict__ W11l,
    ushort* __restrict__ W21h, ushort* __restrict__ W21l,
    float* __restrict__ Wfold, float* __restrict__ bfold) {
  const int b = blockIdx.x;
  if (b < 8)       prepw_body(W02, W02h, W02l, b);
  else if (b < 16) prepw_body(W12, W12h, W12l, b - 8);
  else if (b < 32) packab_body(W11, W11h, W11l, b - 16);
  else if (b < 48) packab_body(W21, W21h, W21l, b - 32);
  else {
    const int t = (b - 48) * 256 + threadIdx.x;  // 0..511
    const int f = t >> 2, o = t & 3;
    float acc = 0.f;
    for (int h = 0; h < HDIM; ++h)
      acc = fmaf(W22[f * HDIM + h], Wf[h * 4 + o], acc);
    Wfold[t] = acc;
    if (t < 4) {
      float a = bf[t];
      for (int h = 0; h < HDIM; ++h) a = fmaf(b22[h], Wf[h * 4 + t], a);
      bfold[t] = a;
    }
  }
}

// ---------------- layer-0 node projection (K=16), VALU ----------------------
__global__ __launch_bounds__(256) void k_node_ab16(const float* __restrict__ x,
                                                   const float* __restrict__ W1,
                                                   const float* __restrict__ b1,
                                                   float* __restrict__ A,
                                                   float* __restrict__ B) {
  __shared__ float s_x[16 * FDIM];
  const int tid = threadIdx.x;
  const int nb = blockIdx.x * 16;
  s_x[tid] = x[(size_t)nb * FDIM + tid];
  __syncthreads();
  const int h = tid & 127;
  const int half = tid >> 7;
  float accA[8], accB[8];
  #pragma unroll
  for (int j = 0; j < 8; ++j) { accA[j] = 0.f; accB[j] = 0.f; }
  #pragma unroll 4
  for (int f = 0; f < FDIM; ++f) {
    const float wt = W1[f * HDIM + h];
    const float wb = W1[(f + FDIM) * HDIM + h];
    const float wd = wt - wb;
    #pragma unroll
    for (int j = 0; j < 8; ++j) {
      const float xv = s_x[(half * 8 + j) * FDIM + f];
      accA[j] = fmaf(xv, wd, accA[j]);
      accB[j] = fmaf(xv, wb, accB[j]);
    }
  }
  const float bias = b1[h];
  #pragma unroll
  for (int j = 0; j < 8; ++j) {
    const size_t idx = (size_t)(nb + half * 8 + j) * HDIM + h;
    A[idx] = accA[j] + bias;
    B[idx] = accB[j];
  }
}

// ---------------- node A|B projection via split-bf16 MFMA (layer 1) ---------
// C[64 x 256] = X[64 x 128] @ Wcat ; cols 0-127 -> A (+b1), 128-255 -> B.
// Input is monotone-encoded uint (layer-0 max output), decoded inline.
__global__ __launch_bounds__(256) void k_node_ab_mfma(
    const unsigned* __restrict__ X, const ushort* __restrict__ Whi,
    const ushort* __restrict__ Wlo, const float* __restrict__ b1,
    float* __restrict__ A, float* __restrict__ B) {
  __shared__ __align__(16) ushort s_hi[64 * 128];
  __shared__ __align__(16) ushort s_lo[64 * 128];
  const int tid = threadIdx.x;
  const int nb = blockIdx.x * 64;

  #pragma unroll
  for (int it = 0; it < 4; ++it) {
    const int idx = tid + it * 256;
    const int row = idx >> 4;
    const int kg8 = idx & 15;
    const int n = nb + row;
    float v[8];
    if (n < NNODES) {
      const unsigned* p = X + (size_t)n * HDIM + kg8 * 8;
      const uint4 u0 = *(const uint4*)p;
      const uint4 u1 = *(const uint4*)(p + 4);
      const unsigned uu[8] = {u0.x, u0.y, u0.z, u0.w, u1.x, u1.y, u1.z, u1.w};
      #pragma unroll
      for (int j = 0; j < 8; ++j)
        v[j] = (uu[j] & 0x80000000u) ? __uint_as_float(uu[j] ^ 0x80000000u) : 0.f;
    } else {
      #pragma unroll
      for (int j = 0; j < 8; ++j) v[j] = 0.f;
    }
    short8 hv, lv;
    split8_tr(v, hv, lv);
    const int unit = row * 16 + (kg8 ^ (row & 15));
    *(short8*)(s_hi + unit * 8) = hv;
    *(short8*)(s_lo + unit * 8) = lv;
  }
  __syncthreads();

  const int l15 = tid & 15;
  const int l4  = (tid >> 4) & 3;
  const int w   = tid >> 6;

  f32x4 acc[4][4];
  #pragma unroll
  for (int rt = 0; rt < 4; ++rt)
    #pragma unroll
    for (int c = 0; c < 4; ++c)
      #pragma unroll
      for (int r = 0; r < 4; ++r) acc[rt][c][r] = 0.f;

  #pragma unroll
  for (int ks = 0; ks < 4; ++ks) {
    short8 wh[4], wl[4];
    #pragma unroll
    for (int ctl = 0; ctl < 4; ++ctl) {
      const int ct_g = w * 4 + ctl;
      const size_t u = ((size_t)(((ct_g * 4 + ks) * 4 + l4) * 16 + l15)) * 8;
      wh[ctl] = *(const short8*)(Whi + u);
      wl[ctl] = *(const short8*)(Wlo + u);
    }
    #pragma unroll
    for (int rt = 0; rt < 4; ++rt) {
      const int unit = (rt * 16 + l15) * 16 + ((ks * 4 + l4) ^ l15);
      const short8 ah = *(const short8*)(s_hi + unit * 8);
      const short8 al = *(const short8*)(s_lo + unit * 8);
      #pragma unroll
      for (int ctl = 0; ctl < 4; ++ctl) {
        acc[rt][ctl] = __builtin_amdgcn_mfma_f32_16x16x32_bf16(al, wh[ctl], acc[rt][ctl], 0, 0, 0);
        acc[rt][ctl] = __builtin_amdgcn_mfma_f32_16x16x32_bf16(ah, wl[ctl], acc[rt][ctl], 0, 0, 0);
        acc[rt][ctl] = __builtin_amdgcn_mfma_f32_16x16x32_bf16(ah, wh[ctl], acc[rt][ctl], 0, 0, 0);
      }
    }
  }

  #pragma unroll
  for (int ctl = 0; ctl < 4; ++ctl) {
    const int col_g = w * 64 + ctl * 16 + l15;
    const bool isA = col_g < HDIM;           // uniform per (w,ctl)
    const float bias = isA ? b1[col_g] : 0.f;
    float* const base = isA ? (A + col_g) : (B + col_g - HDIM);
    #pragma unroll
    for (int rt = 0; rt < 4; ++rt)
      #pragma unroll
      for (int r = 0; r < 4; ++r) {
        const int n = nb + rt * 16 + l4 * 4 + r;
        if (n < NNODES) base[(size_t)n * HDIM] = acc[rt][ctl][r] + bias;
      }
  }
}

// ---------------- fused layer-2 node pipeline -------------------------------
// h2 = relu((S1*scale)@W12 + b12)*alive  (GEMM1, stays in LDS)
// A2|B2 = h2 @ Wcat21 (+b21 on A)        (GEMM2)
__global__ __launch_bounds__(256) void k_node_l2_fused(
    const float* __restrict__ S, const unsigned* __restrict__ cnt,
    const ushort* __restrict__ W12h, const ushort* __restrict__ W12l,
    const float* __restrict__ b12,
    const ushort* __restrict__ W21h, const ushort* __restrict__ W21l,
    const float* __restrict__ b21,
    float* __restrict__ A, float* __restrict__ B) {
  __shared__ __align__(16) ushort s_hi[64 * 128];
  __shared__ __align__(16) ushort s_lo[64 * 128];
  __shared__ float s_m[64 * 132];
  __shared__ float s_scale[64];
  __shared__ float s_alive[64];
  const int tid = threadIdx.x;
  const int nb = blockIdx.x * 64;
  if (tid < 64) {
    const int n = nb + tid;
    const unsigned c = (n < NNODES) ? cnt[n] : 0u;
    s_scale[tid] = c ? 1.f / (float)c : 0.f;
    s_alive[tid] = c ? 1.f : 0.f;
  }
  __syncthreads();

  // stage S*scale -> split LDS
  #pragma unroll
  for (int it = 0; it < 4; ++it) {
    const int idx = tid + it * 256;
    const int row = idx >> 4;
    const int kg8 = idx & 15;
    const int n = nb + row;
    float v[8];
    if (n < NNODES) {
      const float sc = s_scale[row];
      const float* p = S + (size_t)n * HDIM + kg8 * 8;
      const float4 a0 = *(const float4*)p;
      const float4 a1 = *(const float4*)(p + 4);
      v[0] = a0.x * sc; v[1] = a0.y * sc; v[2] = a0.z * sc; v[3] = a0.w * sc;
      v[4] = a1.x * sc; v[5] = a1.y * sc; v[6] = a1.z * sc; v[7] = a1.w * sc;
    } else {
      #pragma unroll
      for (int j = 0; j < 8; ++j) v[j] = 0.f;
    }
    short8 hv, lv;
    split8_tr(v, hv, lv);
    const int unit = row * 16 + (kg8 ^ (row & 15));
    *(short8*)(s_hi + unit * 8) = hv;
    *(short8*)(s_lo + unit * 8) = lv;
  }
  __syncthreads();

  const int l15 = tid & 15;
  const int l4  = (tid >> 4) & 3;
  const int w   = tid >> 6;

  // ---- GEMM1: 128 cols (2 ctl/wave) ----
  {
    f32x4 acc[4][2];
    #pragma unroll
    for (int rt = 0; rt < 4; ++rt)
      #pragma unroll
      for (int c = 0; c < 2; ++c)
        #pragma unroll
        for (int r = 0; r < 4; ++r) acc[rt][c][r] = 0.f;

    #pragma unroll
    for (int ks = 0; ks < 4; ++ks) {
      short8 wh[2], wl[2];
      #pragma unroll
      for (int ctl = 0; ctl < 2; ++ctl) {
        const int ct_g = w * 2 + ctl;
        const size_t u = ((size_t)(((ct_g * 4 + ks) * 4 + l4) * 16 + l15)) * 8;
        wh[ctl] = *(const short8*)(W12h + u);
        wl[ctl] = *(const short8*)(W12l + u);
      }
      #pragma unroll
      for (int rt = 0; rt < 4; ++rt) {
        const int unit = (rt * 16 + l15) * 16 + ((ks * 4 + l4) ^ l15);
        const short8 ah = *(const short8*)(s_hi + unit * 8);
        const short8 al = *(const short8*)(s_lo + unit * 8);
        #pragma unroll
        for (int ctl = 0; ctl < 2; ++ctl) {
          acc[rt][ctl] = __builtin_amdgcn_mfma_f32_16x16x32_bf16(al, wh[ctl], acc[rt][ctl], 0, 0, 0);
          acc[rt][ctl] = __builtin_amdgcn_mfma_f32_16x16x32_bf16(ah, wl[ctl], acc[rt][ctl], 0, 0, 0);
          acc[rt][ctl] = __builtin_amdgcn_mfma_f32_16x16x32_bf16(ah, wh[ctl], acc[rt][ctl], 0, 0, 0);
        }
      }
    }

    // dump h2 = relu(acc+bias)*alive to s_m
    const float bb0 = b12[w * 32 + l15];
    const float bb1 = b12[w * 32 + 16 + l15];
    #pragma unroll
    for (int rt = 0; rt < 4; ++rt)
      #pragma unroll
      for (int ctl = 0; ctl < 2; ++ctl)
        #pragma unroll
        for (int r = 0; r < 4; ++r) {
          const int row = rt * 16 + l4 * 4 + r;
          s_m[row * 132 + w * 32 + ctl * 16 + l15] =
              fmaxf(acc[rt][ctl][r] + (ctl ? bb1 : bb0), 0.f) * s_alive[row];
        }
  }
  __syncthreads();  // all GEMM1 LDS reads + s_m writes done

  // restage h2 -> split LDS (overwrite s_hi/s_lo)
  #pragma unroll
  for (int it = 0; it < 4; ++it) {
    const int idx = tid + it * 256;
    const int row = idx >> 4;
    const int kg8 = idx & 15;
    const float* p = s_m + row * 132 + kg8 * 8;
    float v[8];
    const float4 a0 = *(const float4*)p;
    const float4 a1 = *(const float4*)(p + 4);
    v[0] = a0.x; v[1] = a0.y; v[2] = a0.z; v[3] = a0.w;
    v[4] = a1.x; v[5] = a1.y; v[6] = a1.z; v[7] = a1.w;
    short8 hv, lv;
    split8_tr(v, hv, lv);
    const int unit = row * 16 + (kg8 ^ (row & 15));
    *(short8*)(s_hi + unit * 8) = hv;
    *(short8*)(s_lo + unit * 8) = lv;
  }
  __syncthreads();

  // ---- GEMM2: 256 cols (4 ctl/wave) ----
  f32x4 acc2[4][4];
  #pragma unroll
  for (int rt = 0; rt < 4; ++rt)
    #pragma unroll
    for (int c = 0; c < 4; ++c)
      #pragma unroll
      for (int r = 0; r < 4; ++r) acc2[rt][c][r] = 0.f;

  #pragma unroll
  for (int ks = 0; ks < 4; ++ks) {
    short8 wh[4], wl[4];
    #pragma unroll
    for (int ctl = 0; ctl < 4; ++ctl) {
      const int ct_g = w * 4 + ctl;
      const size_t u = ((size_t)(((ct_g * 4 + ks) * 4 + l4) * 16 + l15)) * 8;
      wh[ctl] = *(const short8*)(W21h + u);
      wl[ctl] = *(const short8*)(W21l + u);
    }
    #pragma unroll
    for (int rt = 0; rt < 4; ++rt) {
      const int unit = (rt * 16 + l15) * 16 + ((ks * 4 + l4) ^ l15);
      const short8 ah = *(const short8*)(s_hi + unit * 8);
      const short8 al = *(const short8*)(s_lo + unit * 8);
      #pragma unroll
      for (int ctl = 0; ctl < 4; ++ctl) {
        acc2[rt][ctl] = __builtin_amdgcn_mfma_f32_16x16x32_bf16(al, wh[ctl], acc2[rt][ctl], 0, 0, 0);
        acc2[rt][ctl] = __builtin_amdgcn_mfma_f32_16x16x32_bf16(ah, wl[ctl], acc2[rt][ctl], 0, 0, 0);
        acc2[rt][ctl] = __builtin_amdgcn_mfma_f32_16x16x32_bf16(ah, wh[ctl], acc2[rt][ctl], 0, 0, 0);
      }
    }
  }

  #pragma unroll
  for (int ctl = 0; ctl < 4; ++ctl) {
    const int col_g = w * 64 + ctl * 16 + l15;
    const bool isA = col_g < HDIM;
    const float bias = isA ? b21[col_g] : 0.f;
    float* const base = isA ? (A + col_g) : (B + col_g - HDIM);
    #pragma unroll
    for (int rt = 0; rt < 4; ++rt)
      #pragma unroll
      for (int r = 0; r < 4; ++r) {
        const int n = nb + rt * 16 + l4 * 4 + r;
        if (n < NNODES) base[(size_t)n * HDIM] = acc2[rt][ctl][r] + bias;
      }
  }
}

// ---------------- layer 0: split-bf16 MFMA edge GEMM + LDS segmented max ----
__global__ __launch_bounds__(256) void k_edge_l0_mfma(
    const float* __restrict__ A0, const float* __restrict__ B0,
    const int* __restrict__ ssrc, const int* __restrict__ sdst,
    const ushort* __restrict__ Whi, const ushort* __restrict__ Wlo,
    const float* __restrict__ b2, unsigned* __restrict__ outenc) {
  __shared__ __align__(16) char s_un[4 * 64 * 33 * 4];
  __shared__ int s_dstA[64];
  __shared__ int s_srcA[64];
  ushort* s_thi = (ushort*)s_un;
  ushort* s_tlo = (ushort*)(s_un + 16384);
  float*  s_m   = (float*)s_un;

  const int tid = threadIdx.x;
  const int eb = blockIdx.x * 64;
  if (tid < 64) s_dstA[tid] = sdst[eb + tid];
  else if (tid < 128) s_srcA[tid - 64] = ssrc[eb + tid - 64];
  __syncthreads();

  #pragma unroll
  for (int it = 0; it < 4; ++it) {
    const int idx = tid + it * 256;
    const int e = idx >> 4;
    const int kg8 = idx & 15;
    const int k0 = kg8 * 8;
    const float* ap = A0 + (size_t)s_dstA[e] * HDIM + k0;
    const float* bp = B0 + (size_t)s_srcA[e] * HDIM + k0;
    const float4 a0 = *(const float4*)ap;
    const float4 a1 = *(const float4*)(ap + 4);
    const float4 b0 = *(const float4*)bp;
    const float4 b1 = *(const float4*)(bp + 4);
    float v[8] = {fmaxf(a0.x + b0.x, 0.f), fmaxf(a0.y + b0.y, 0.f),
                  fmaxf(a0.z + b0.z, 0.f), fmaxf(a0.w + b0.w, 0.f),
                  fmaxf(a1.x + b1.x, 0.f), fmaxf(a1.y + b1.y, 0.f),
                  fmaxf(a1.z + b1.z, 0.f), fmaxf(a1.w + b1.w, 0.f)};
    short8 hv, lv;
    split8_tr(v, hv, lv);
    const int unit = e * 16 + (kg8 ^ (e & 15));
    *(short8*)(s_thi + unit * 8) = hv;
    *(short8*)(s_tlo + unit * 8) = lv;
  }
  __syncthreads();

  const int l15 = tid & 15;
  const int l4  = (tid >> 4) & 3;
  const int w   = tid >> 6;

  f32x4 acc[4][2];
  #pragma unroll
  for (int rt = 0; rt < 4; ++rt)
    #pragma unroll
    for (int c = 0; c < 2; ++c)
      #pragma unroll
      for (int r = 0; r < 4; ++r) acc[rt][c][r] = 0.f;

  #pragma unroll
  for (int ks = 0; ks < 4; ++ks) {
    short8 wh[2], wl[2];
    #pragma unroll
    for (int ctl = 0; ctl < 2; ++ctl) {
      const int ct_g = w * 2 + ctl;
      const size_t u = ((size_t)(((ct_g * 4 + ks) * 4 + l4) * 16 + l15)) * 8;
      wh[ctl] = *(const short8*)(Whi + u);
      wl[ctl] = *(const short8*)(Wlo + u);
    }
    #pragma unroll
    for (int rt = 0; rt < 4; ++rt) {
      const int e = rt * 16 + l15;
      const int unit = e * 16 + ((ks * 4 + l4) ^ l15);
      const short8 ah = *(const short8*)(s_thi + unit * 8);
      const short8 al = *(const short8*)(s_tlo + unit * 8);
      #pragma unroll
      for (int ctl = 0; ctl < 2; ++ctl) {
        acc[rt][ctl] = __builtin_amdgcn_mfma_f32_16x16x32_bf16(al, wh[ctl], acc[rt][ctl], 0, 0, 0);
        acc[rt][ctl] = __builtin_amdgcn_mfma_f32_16x16x32_bf16(ah, wl[ctl], acc[rt][ctl], 0, 0, 0);
        acc[rt][ctl] = __builtin_amdgcn_mfma_f32_16x16x32_bf16(ah, wh[ctl], acc[rt][ctl], 0, 0, 0);
      }
    }
  }
  __syncthreads();

  const float bb0 = b2[w * 32 + l15];
  const float bb1 = b2[w * 32 + 16 + l15];
  float* sm = s_m + w * (64 * 33);
  #pragma unroll
  for (int rt = 0; rt < 4; ++rt)
    #pragma unroll
    for (int ctl = 0; ctl < 2; ++ctl)
      #pragma unroll
      for (int r = 0; r < 4; ++r)
        sm[(rt * 16 + l4 * 4 + r) * 33 + ctl * 16 + l15] =
            acc[rt][ctl][r] + (ctl ? bb1 : bb0);
  __syncthreads();

  {
    const int l = tid & 63;
    const int col = l & 31;
    const int g = l >> 5;
    const int e0 = g * 32;
    int curd = s_dstA[e0];
    float run = sm[e0 * 33 + col];
    for (int e = e0 + 1; e < e0 + 32; ++e) {
      const int d = s_dstA[e];
      const float v = sm[e * 33 + col];
      if (d == curd) run = fmaxf(run, v);
      else {
        atomicMax(outenc + (size_t)curd * HDIM + w * 32 + col, enc_f32(run));
        curd = d; run = v;
      }
    }
    atomicMax(outenc + (size_t)curd * HDIM + w * 32 + col, enc_f32(run));
  }
}

// ---------------- layer-1 mean: wave-per-node CSR sum, float2/lane ----------
__global__ __launch_bounds__(256) void k_seg_mean(const float* __restrict__ A,
                                                  const float* __restrict__ B,
                                                  const int* __restrict__ ssrc,
                                                  const unsigned* __restrict__ endv,
                                                  const unsigned* __restrict__ cnt,
                                                  float* __restrict__ S) {
  const int tid = threadIdx.x;
  const int n = blockIdx.x * 4 + (tid >> 6);
  const int lane = tid & 63;
  const unsigned end = endv[n];
  unsigned e = end - cnt[n];
  const float2 a = *(const float2*)(A + (size_t)n * HDIM + lane * 2);
  float sx = 0.f, sy = 0.f;
  for (; e + 8 <= end; e += 8) {
    int s[8];
    #pragma unroll
    for (int k = 0; k < 8; ++k) s[k] = ssrc[e + k];
    float2 v[8];
    #pragma unroll
    for (int k = 0; k < 8; ++k)
      v[k] = *(const float2*)(B + (size_t)s[k] * HDIM + lane * 2);
    #pragma unroll
    for (int k = 0; k < 8; ++k) {
      sx += fmaxf(a.x + v[k].x, 0.f);
      sy += fmaxf(a.y + v[k].y, 0.f);
    }
  }
  for (; e + 2 <= end; e += 2) {
    const int s0 = ssrc[e], s1 = ssrc[e + 1];
    const float2 v0 = *(const float2*)(B + (size_t)s0 * HDIM + lane * 2);
    const float2 v1 = *(const float2*)(B + (size_t)s1 * HDIM + lane * 2);
    sx += fmaxf(a.x + v0.x, 0.f) + fmaxf(a.x + v1.x, 0.f);
    sy += fmaxf(a.y + v0.y, 0.f) + fmaxf(a.y + v1.y, 0.f);
  }
  for (; e < end; ++e) {
    const float2 v = *(const float2*)(B + (size_t)ssrc[e] * HDIM + lane * 2);
    sx += fmaxf(a.x + v.x, 0.f);
    sy += fmaxf(a.y + v.y, 0.f);
  }
  float2 o; o.x = sx; o.y = sy;
  *(float2*)(S + (size_t)n * HDIM + lane * 2) = o;
}

// ---------------- layer-2 mean fused with final fc --------------------------
// out[n] = (mean_e relu(A2[n]+B2[src])) @ Wfold + bfold ; deg==0 -> bf
__global__ __launch_bounds__(256) void k_seg_final(const float* __restrict__ A,
                                                   const float* __restrict__ B,
                                                   const int* __restrict__ ssrc,
                                                   const unsigned* __restrict__ endv,
                                                   const unsigned* __restrict__ cnt,
                                                   const float* __restrict__ Wfold,
                                                   const float* __restrict__ bfold,
                                                   const float* __restrict__ bf,
                                                   float* __restrict__ out) {
  const int tid = threadIdx.x;
  const int n = blockIdx.x * 4 + (tid >> 6);
  const int lane = tid & 63;
  const unsigned deg = cnt[n];
  if (deg == 0) {
    if (lane == 0) {
      float4 o; o.x = bf[0]; o.y = bf[1]; o.z = bf[2]; o.w = bf[3];
      ((float4*)out)[n] = o;
    }
    return;
  }
  const unsigned end = endv[n];
  unsigned e = end - deg;
  const float2 a = *(const float2*)(A + (size_t)n * HDIM + lane * 2);
  float sx = 0.f, sy = 0.f;
  for (; e + 8 <= end; e += 8) {
    int s[8];
    #pragma unroll
    for (int k = 0; k < 8; ++k) s[k] = ssrc[e + k];
    float2 v[8];
    #pragma unroll
    for (int k = 0; k < 8; ++k)
      v[k] = *(const float2*)(B + (size_t)s[k] * HDIM + lane * 2);
    #pragma unroll
    for (int k = 0; k < 8; ++k) {
      sx += fmaxf(a.x + v[k].x, 0.f);
      sy += fmaxf(a.y + v[k].y, 0.f);
    }
  }
  for (; e < end; ++e) {
    const float2 v = *(const float2*)(B + (size_t)ssrc[e] * HDIM + lane * 2);
    sx += fmaxf(a.x + v.x, 0.f);
    sy += fmaxf(a.y + v.y, 0.f);
  }
  const float inv = 1.f / (float)deg;
  const float vx = sx * inv, vy = sy * inv;
  const float4 w0 = ((const float4*)Wfold)[lane * 2];
  const float4 w1 = ((const float4*)Wfold)[lane * 2 + 1];
  float p0 = fmaf(vx, w0.x, vy * w1.x);
  float p1 = fmaf(vx, w0.y, vy * w1.y);
  float p2 = fmaf(vx, w0.z, vy * w1.z);
  float p3 = fmaf(vx, w0.w, vy * w1.w);
  #pragma unroll
  for (int off = 32; off; off >>= 1) {
    p0 += __shfl_xor(p0, off);
    p1 += __shfl_xor(p1, off);
    p2 += __shfl_xor(p2, off);
    p3 += __shfl_xor(p3, off);
  }
  if (lane == 0) {
    float4 o;
    o.x = p0 + bfold[0]; o.y = p1 + bfold[1];
    o.z = p2 + bfold[2]; o.w = p3 + bfold[3];
    ((float4*)out)[n] = o;
  }
}

// ----------------------------------------------------------------------------
extern "C" void kernel_launch(void* const* d_in, const int* in_sizes, int n_in,
                              void* d_out, int out_size, void* d_ws, size_t ws_size,
                              hipStream_t stream) {
  const float* x   = (const float*)d_in[0];
  // d_in[1] = edge_attr: unused in math
  const int*   eidx = (const int*)d_in[2];
  const float* W01 = (const float*)d_in[3];
  const float* b01 = (const float*)d_in[4];
  const float* W02 = (const float*)d_in[5];
  const float* b02 = (const float*)d_in[6];
  const float* W11 = (const float*)d_in[7];
  const float* b11 = (const float*)d_in[8];
  const float* W12 = (const float*)d_in[9];
  const float* b12 = (const float*)d_in[10];
  const float* W21 = (const float*)d_in[11];
  const float* b21 = (const float*)d_in[12];
  const float* W22 = (const float*)d_in[13];
  const float* b22 = (const float*)d_in[14];
  const float* Wf  = (const float*)d_in[15];
  const float* bf  = (const float*)d_in[16];
  float* out = (float*)d_out;
  char* ws = (char*)d_ws;

  float* buf0 = (float*)(ws + OFF_BUF0);
  float* buf1 = (float*)(ws + OFF_BUF1);
  float* buf2 = (float*)(ws + OFF_BUF2);
  unsigned* cnt    = (unsigned*)(ws + OFF_CNT);
  unsigned* cursor = (unsigned*)(ws + OFF_CUR);
  unsigned* csum   = (unsigned*)(ws + OFF_CSUM);
  unsigned* coff   = (unsigned*)(ws + OFF_COFF);
  float* Wfold = (float*)(ws + OFF_WFOLD);
  float* bfold = (float*)(ws + OFF_BFOLD);
  int* flag  = (int*)(ws + OFF_FLAG);
  int* ssrc  = (int*)(ws + OFF_SSRC);
  int* sdst  = (int*)(ws + OFF_SDST);
  ushort* W02h = (ushort*)(ws + OFF_W02H);
  ushort* W02l = (ushort*)(ws + OFF_W02L);
  ushort* W12h = (ushort*)(ws + OFF_W12H);
  ushort* W12l = (ushort*)(ws + OFF_W12L);
  ushort* W11h = (ushort*)(ws + OFF_W11H);
  ushort* W11l = (ushort*)(ws + OFF_W11L);
  ushort* W21h = (ushort*)(ws + OFF_W21H);
  ushort* W21l = (ushort*)(ws + OFF_W21L);

  // ---- counting sort of edges by dst (CSR) + weight prep ----
  k_init<<<NPAD / 256, 256, 0, stream>>>(eidx, flag, cnt);
  k_count<<<NEDGES / 256, 256, 0, stream>>>(eidx, flag, cnt);
  k_scan1<<<NCH, 256, 0, stream>>>(cnt, csum);
  k_scan2<<<1, 64, 0, stream>>>(csum, coff);
  k_scan3<<<NCH, 256, 0, stream>>>(cnt, coff, cursor);
  k_scatter<<<NEDGES / 256, 256, 0, stream>>>(eidx, flag, cursor, ssrc, sdst);
  // after scatter: cursor[n] == segment end offset of node n
  k_prep_all<<<50, 256, 0, stream>>>(W02, W12, W11, W21, W22, Wf, b22, bf,
                                     W02h, W02l, W12h, W12l, W11h, W11l,
                                     W21h, W21l, Wfold, bfold);

  // ---- layer 0 (max aggr) ----
  k_node_ab16<<<NNODES / 16, 256, 0, stream>>>(x, W01, b01, buf0, buf1);
  hipMemsetAsync(buf2, 0, NHB, stream);
  k_edge_l0_mfma<<<NEDGES / 64, 256, 0, stream>>>(buf0, buf1, ssrc, sdst,
                                                  W02h, W02l, b02, (unsigned*)buf2);
  // buf2 = encoded h1 (decode fused into next stage)

  // ---- layer 1 (mean aggr) ----
  k_node_ab_mfma<<<NBLK64, 256, 0, stream>>>((const unsigned*)buf2, W11h, W11l,
                                             b11, buf0, buf1);
  k_seg_mean<<<NNODES / 4, 256, 0, stream>>>(buf0, buf1, ssrc, cursor, cnt, buf2);

  // ---- layer 2: h2-GEMM + A2|B2-GEMM fused, then mean+final fused ----
  k_node_l2_fused<<<NBLK64, 256, 0, stream>>>(buf2, cnt, W12h, W12l, b12,
                                              W21h, W21l, b21, buf0, buf1);
  k_seg_final<<<NNODES / 4, 256, 0, stream>>>(buf0, buf1, ssrc, cursor, cnt,
                                              Wfold, bfold, bf, out);

  (void)in_sizes; (void)n_in; (void)out_size; (void)ws_size;
}

// Round 6
// 468.272 us; speedup vs baseline: 6.8405x; 1.0722x over previous
//
#include <hip/hip_runtime.h>
#include <stdint.h>

#define NNODES 50000
#define NEDGES 800000
#define FDIM 16
#define HDIM 128
#define NPAD 50176            // 98 * 512, padded node count for the scan
#define NCH 98                // scan chunks of 512
#define NBLK64 782            // ceil(NNODES/64)

typedef __attribute__((ext_vector_type(8))) short short8;
typedef __attribute__((ext_vector_type(4))) float f32x4;

static constexpr size_t NH  = (size_t)NNODES * HDIM;   // 6.4e6 elems
static constexpr size_t NHB = NH * sizeof(float);      // 25.6 MB

// workspace layout (16B aligned)
static constexpr size_t OFF_BUF0  = 0;                        // fp32 A/S buffers
static constexpr size_t OFF_BUF1  = NHB;
static constexpr size_t OFF_BUF2  = 2 * NHB;                  // enc h1
static constexpr size_t OFF_BFB   = 3 * NHB;                  // bf16 B rows (N x 128 u16)
static constexpr size_t OFF_CNT   = OFF_BFB + NH * 2;         // NPAD x u32
static constexpr size_t OFF_CUR   = OFF_CNT + NPAD * 4;       // NPAD x u32 (end offsets)
static constexpr size_t OFF_CSUM  = OFF_CUR + NPAD * 4;       // NCH x u32 (pad 512)
static constexpr size_t OFF_COFF  = OFF_CSUM + 512;           // NCH x u32
static constexpr size_t OFF_WFOLD = OFF_COFF + 512;           // 128*4 f32
static constexpr size_t OFF_BFOLD = OFF_WFOLD + 2048;         // 4 f32
static constexpr size_t OFF_FLAG  = OFF_BFOLD + 256;          // 1 int
static constexpr size_t OFF_SSRC  = OFF_FLAG + 256;           // E x i32 (sorted by dst)
static constexpr size_t OFF_SDST  = OFF_SSRC + (size_t)NEDGES * 4;
static constexpr size_t OFF_W02H  = OFF_SDST + (size_t)NEDGES * 4;  // 2048 units x 16B
static constexpr size_t OFF_W02L  = OFF_W02H + 32768;
static constexpr size_t OFF_W12H  = OFF_W02L + 32768;               // 2048 units
static constexpr size_t OFF_W12L  = OFF_W12H + 32768;
static constexpr size_t OFF_W11H  = OFF_W12L + 32768;               // 4096 units
static constexpr size_t OFF_W11L  = OFF_W11H + 65536;
static constexpr size_t OFF_W21H  = OFF_W11L + 65536;
static constexpr size_t OFF_W21L  = OFF_W21H + 65536;

__device__ inline unsigned enc_f32(float m) {
  unsigned u = __float_as_uint(m);
  return (u & 0x80000000u) ? ~u : (u | 0x80000000u);  // monotone encoding, enc>0 always
}

// rne fp32 -> bf16
__device__ inline ushort bf16_rne(float v) {
  const unsigned u = __float_as_uint(v);
  return (ushort)((u + 0x7fffu + ((u >> 16) & 1u)) >> 16);
}

// rne split (weights only, prep-time)
__device__ inline void bf16_split(float v, ushort& h, ushort& l) {
  unsigned u = __float_as_uint(v);
  unsigned hb = (u + 0x7fffu + ((u >> 16) & 1u)) & 0xffff0000u;
  h = (ushort)(hb >> 16);
  float r = v - __uint_as_float(hb);
  unsigned ur = __float_as_uint(r);
  l = (ushort)((ur + 0x7fffu + ((ur >> 16) & 1u)) >> 16);
}

// cheap truncation split of 8 floats -> bf16 hi/lo fragments (pair-packed)
__device__ inline void split8_tr(const float v[8], short8& hv, short8& lv) {
  unsigned hp[4], lp[4];
  #pragma unroll
  for (int k = 0; k < 4; ++k) {
    const unsigned u0 = __float_as_uint(v[2 * k]);
    const unsigned u1 = __float_as_uint(v[2 * k + 1]);
    const unsigned h0 = u0 & 0xffff0000u;
    const unsigned h1 = u1 & 0xffff0000u;
    const float r0 = v[2 * k]     - __uint_as_float(h0);
    const float r1 = v[2 * k + 1] - __uint_as_float(h1);
    hp[k] = h1 | (h0 >> 16);
    lp[k] = (__float_as_uint(r1) & 0xffff0000u) | (__float_as_uint(r0) >> 16);
  }
  hv = *(short8*)hp;
  lv = *(short8*)lp;
}

// ---------------- init: zero cnt + edge-index dtype detect ------------------
__global__ __launch_bounds__(256) void k_init(const int* __restrict__ raw,
                                              int* __restrict__ flag,
                                              unsigned* __restrict__ cnt) {
  const int i = blockIdx.x * 256 + threadIdx.x;
  cnt[i] = 0u;                       // grid covers NPAD exactly
  if (blockIdx.x == 0 && threadIdx.x == 0) {
    int is64 = 1;
    #pragma unroll
    for (int k = 1; k < 64; k += 2)
      if (raw[k] != 0) is64 = 0;     // int64 => high dwords zero
    *flag = is64;
  }
}

__global__ __launch_bounds__(256) void k_count(const int* __restrict__ raw,
                                               const int* __restrict__ flag,
                                               unsigned* __restrict__ cnt) {
  const size_t e = (size_t)blockIdx.x * 256 + threadIdx.x;
  const int d = (*flag) ? raw[2 * ((size_t)NEDGES + e)] : raw[NEDGES + e];
  atomicAdd(&cnt[d], 1u);
}

// ---------------- prefix scan over cnt -> cursor (exclusive offsets) --------
__global__ __launch_bounds__(256) void k_scan1(const unsigned* __restrict__ cnt,
                                               unsigned* __restrict__ csum) {
  __shared__ unsigned s[256];
  const int t = threadIdx.x, b = blockIdx.x;
  s[t] = cnt[b * 512 + t] + cnt[b * 512 + 256 + t];
  __syncthreads();
  for (int off = 128; off; off >>= 1) {
    if (t < off) s[t] += s[t + off];
    __syncthreads();
  }
  if (t == 0) csum[b] = s[0];
}

__global__ void k_scan2(const unsigned* __restrict__ csum,
                        unsigned* __restrict__ coff) {
  if (threadIdx.x == 0) {
    unsigned r = 0;
    for (int i = 0; i < NCH; ++i) { coff[i] = r; r += csum[i]; }
  }
}

__global__ __launch_bounds__(256) void k_scan3(const unsigned* __restrict__ cnt,
                                               const unsigned* __restrict__ coff,
                                               unsigned* __restrict__ cursor) {
  __shared__ unsigned s[256];
  const int t = threadIdx.x, b = blockIdx.x;
  const int base = b * 512;
  const unsigned c0 = cnt[base + 2 * t], c1 = cnt[base + 2 * t + 1];
  s[t] = c0 + c1;
  __syncthreads();
  for (int off = 1; off < 256; off <<= 1) {
    unsigned v = s[t];
    if (t >= off) v += s[t - off];
    __syncthreads();
    s[t] = v;
    __syncthreads();
  }
  const unsigned o = coff[b] + s[t] - (c0 + c1);  // exclusive pair prefix
  cursor[base + 2 * t] = o;
  cursor[base + 2 * t + 1] = o + c0;
}

__global__ __launch_bounds__(256) void k_scatter(const int* __restrict__ raw,
                                                 const int* __restrict__ flag,
                                                 unsigned* __restrict__ cursor,
                                                 int* __restrict__ ssrc,
                                                 int* __restrict__ sdst) {
  const size_t e = (size_t)blockIdx.x * 256 + threadIdx.x;
  int s, d;
  if (*flag) { s = raw[2 * e]; d = raw[2 * ((size_t)NEDGES + e)]; }
  else       { s = raw[e];     d = raw[NEDGES + e]; }
  const unsigned p = atomicAdd(&cursor[d], 1u);  // cursor ends at segment END
  ssrc[p] = s;
  sdst[p] = d;
}

// ---------------- all weight prep in ONE kernel -----------------------------
__device__ inline void prepw_body(const float* __restrict__ W2,
                                  ushort* __restrict__ Whi,
                                  ushort* __restrict__ Wlo, int blk) {
  const int gid = blk * 256 + threadIdx.x;   // 0..2047
  const int row = gid & 15;
  const int kg  = (gid >> 4) & 3;
  const int ks  = (gid >> 6) & 3;
  const int ct  = gid >> 8;
  const int col = ct * 16 + row;
  const int k0  = ks * 32 + kg * 8;
  short8 hv, lv;
  #pragma unroll
  for (int j = 0; j < 8; ++j) {
    ushort h, l;
    bf16_split(W2[(size_t)(k0 + j) * HDIM + col], h, l);
    hv[j] = (short)h; lv[j] = (short)l;
  }
  *(short8*)(Whi + (size_t)gid * 8) = hv;
  *(short8*)(Wlo + (size_t)gid * 8) = lv;
}

__device__ inline void packab_body(const float* __restrict__ W1,
                                   ushort* __restrict__ Whi,
                                   ushort* __restrict__ Wlo, int blk) {
  const int gid = blk * 256 + threadIdx.x;   // 0..4095
  const int row = gid & 15;
  const int kg  = (gid >> 4) & 3;
  const int ks  = (gid >> 6) & 3;
  const int ct  = gid >> 8;                   // 0..15
  const int col = ct * 16 + row;
  const int k0  = ks * 32 + kg * 8;
  short8 hv, lv;
  #pragma unroll
  for (int j = 0; j < 8; ++j) {
    const int k = k0 + j;
    float v;
    if (col < HDIM) v = W1[(size_t)k * HDIM + col] - W1[(size_t)(k + HDIM) * HDIM + col];
    else            v = W1[(size_t)(k + HDIM) * HDIM + (col - HDIM)];
    ushort h, l;
    bf16_split(v, h, l);
    hv[j] = (short)h; lv[j] = (short)l;
  }
  *(short8*)(Whi + (size_t)gid * 8) = hv;
  *(short8*)(Wlo + (size_t)gid * 8) = lv;
}

__global__ __launch_bounds__(256) void k_prep_all(
    const float* __restrict__ W02, const float* __restrict__ W12,
    const float* __restrict__ W11, const float* __restrict__ W21,
    const float* __restrict__ W22, const float* __restrict__ Wf,
    const float* __restrict__ b22, const float* __restrict__ bf,
    ushort* __restrict__ W02h, ushort* __restrict__ W02l,
    ushort* __restrict__ W12h, ushort* __restrict__ W12l,
    ushort* __restrict__ W11h, ushort* __restrict__ W11l,
    ushort* __restrict__ W21h, ushort* __restrict__ W21l,
    float* __restrict__ Wfold, float* __restrict__ bfold) {
  const int b = blockIdx.x;
  if (b < 8)       prepw_body(W02, W02h, W02l, b);
  else if (b < 16) prepw_body(W12, W12h, W12l, b - 8);
  else if (b < 32) packab_body(W11, W11h, W11l, b - 16);
  else if (b < 48) packab_body(W21, W21h, W21l, b - 32);
  else {
    const int t = (b - 48) * 256 + threadIdx.x;  // 0..511
    const int f = t >> 2, o = t & 3;
    float acc = 0.f;
    for (int h = 0; h < HDIM; ++h)
      acc = fmaf(W22[f * HDIM + h], Wf[h * 4 + o], acc);
    Wfold[t] = acc;
    if (t < 4) {
      float a = bf[t];
      for (int h = 0; h < HDIM; ++h) a = fmaf(b22[h], Wf[h * 4 + t], a);
      bfold[t] = a;
    }
  }
}

// ---------------- layer-0 node projection (K=16), VALU ----------------------
// A fp32 (dst-side), B bf16 rne (src-side gather operand)
__global__ __launch_bounds__(256) void k_node_ab16(const float* __restrict__ x,
                                                   const float* __restrict__ W1,
                                                   const float* __restrict__ b1,
                                                   float* __restrict__ A,
                                                   ushort* __restrict__ Bb) {
  __shared__ float s_x[16 * FDIM];
  const int tid = threadIdx.x;
  const int nb = blockIdx.x * 16;
  s_x[tid] = x[(size_t)nb * FDIM + tid];
  __syncthreads();
  const int h = tid & 127;
  const int half = tid >> 7;
  float accA[8], accB[8];
  #pragma unroll
  for (int j = 0; j < 8; ++j) { accA[j] = 0.f; accB[j] = 0.f; }
  #pragma unroll 4
  for (int f = 0; f < FDIM; ++f) {
    const float wt = W1[f * HDIM + h];
    const float wb = W1[(f + FDIM) * HDIM + h];
    const float wd = wt - wb;
    #pragma unroll
    for (int j = 0; j < 8; ++j) {
      const float xv = s_x[(half * 8 + j) * FDIM + f];
      accA[j] = fmaf(xv, wd, accA[j]);
      accB[j] = fmaf(xv, wb, accB[j]);
    }
  }
  const float bias = b1[h];
  #pragma unroll
  for (int j = 0; j < 8; ++j) {
    const size_t idx = (size_t)(nb + half * 8 + j) * HDIM + h;
    A[idx] = accA[j] + bias;
    Bb[idx] = bf16_rne(accB[j]);
  }
}

// ---------------- node A|B projection via split-bf16 MFMA (layer 1) ---------
// C[64 x 256] = X[64 x 128] @ Wcat ; cols 0-127 -> A fp32 (+b1), 128-255 -> B bf16.
// Input is monotone-encoded uint (layer-0 max output), decoded inline.
__global__ __launch_bounds__(256) void k_node_ab_mfma(
    const unsigned* __restrict__ X, const ushort* __restrict__ Whi,
    const ushort* __restrict__ Wlo, const float* __restrict__ b1,
    float* __restrict__ A, ushort* __restrict__ Bb) {
  __shared__ __align__(16) ushort s_hi[64 * 128];
  __shared__ __align__(16) ushort s_lo[64 * 128];
  const int tid = threadIdx.x;
  const int nb = blockIdx.x * 64;

  #pragma unroll
  for (int it = 0; it < 4; ++it) {
    const int idx = tid + it * 256;
    const int row = idx >> 4;
    const int kg8 = idx & 15;
    const int n = nb + row;
    float v[8];
    if (n < NNODES) {
      const unsigned* p = X + (size_t)n * HDIM + kg8 * 8;
      const uint4 u0 = *(const uint4*)p;
      const uint4 u1 = *(const uint4*)(p + 4);
      const unsigned uu[8] = {u0.x, u0.y, u0.z, u0.w, u1.x, u1.y, u1.z, u1.w};
      #pragma unroll
      for (int j = 0; j < 8; ++j)
        v[j] = (uu[j] & 0x80000000u) ? __uint_as_float(uu[j] ^ 0x80000000u) : 0.f;
    } else {
      #pragma unroll
      for (int j = 0; j < 8; ++j) v[j] = 0.f;
    }
    short8 hv, lv;
    split8_tr(v, hv, lv);
    const int unit = row * 16 + (kg8 ^ (row & 15));
    *(short8*)(s_hi + unit * 8) = hv;
    *(short8*)(s_lo + unit * 8) = lv;
  }
  __syncthreads();

  const int l15 = tid & 15;
  const int l4  = (tid >> 4) & 3;
  const int w   = tid >> 6;

  f32x4 acc[4][4];
  #pragma unroll
  for (int rt = 0; rt < 4; ++rt)
    #pragma unroll
    for (int c = 0; c < 4; ++c)
      #pragma unroll
      for (int r = 0; r < 4; ++r) acc[rt][c][r] = 0.f;

  #pragma unroll
  for (int ks = 0; ks < 4; ++ks) {
    short8 wh[4], wl[4];
    #pragma unroll
    for (int ctl = 0; ctl < 4; ++ctl) {
      const int ct_g = w * 4 + ctl;
      const size_t u = ((size_t)(((ct_g * 4 + ks) * 4 + l4) * 16 + l15)) * 8;
      wh[ctl] = *(const short8*)(Whi + u);
      wl[ctl] = *(const short8*)(Wlo + u);
    }
    #pragma unroll
    for (int rt = 0; rt < 4; ++rt) {
      const int unit = (rt * 16 + l15) * 16 + ((ks * 4 + l4) ^ l15);
      const short8 ah = *(const short8*)(s_hi + unit * 8);
      const short8 al = *(const short8*)(s_lo + unit * 8);
      #pragma unroll
      for (int ctl = 0; ctl < 4; ++ctl) {
        acc[rt][ctl] = __builtin_amdgcn_mfma_f32_16x16x32_bf16(al, wh[ctl], acc[rt][ctl], 0, 0, 0);
        acc[rt][ctl] = __builtin_amdgcn_mfma_f32_16x16x32_bf16(ah, wl[ctl], acc[rt][ctl], 0, 0, 0);
        acc[rt][ctl] = __builtin_amdgcn_mfma_f32_16x16x32_bf16(ah, wh[ctl], acc[rt][ctl], 0, 0, 0);
      }
    }
  }

  #pragma unroll
  for (int ctl = 0; ctl < 4; ++ctl) {
    const int col_g = w * 64 + ctl * 16 + l15;
    if (col_g < HDIM) {
      const float bias = b1[col_g];
      #pragma unroll
      for (int rt = 0; rt < 4; ++rt)
        #pragma unroll
        for (int r = 0; r < 4; ++r) {
          const int n = nb + rt * 16 + l4 * 4 + r;
          if (n < NNODES) A[(size_t)n * HDIM + col_g] = acc[rt][ctl][r] + bias;
        }
    } else {
      const int cb = col_g - HDIM;
      #pragma unroll
      for (int rt = 0; rt < 4; ++rt)
        #pragma unroll
        for (int r = 0; r < 4; ++r) {
          const int n = nb + rt * 16 + l4 * 4 + r;
          if (n < NNODES) Bb[(size_t)n * HDIM + cb] = bf16_rne(acc[rt][ctl][r]);
        }
    }
  }
}

// ---------------- fused layer-2 node pipeline -------------------------------
// h2 = relu((S1*scale)@W12 + b12)*alive  (GEMM1, stays in LDS)
// A2|B2 = h2 @ Wcat21 (+b21 on A) ; A2 fp32, B2 bf16
__global__ __launch_bounds__(256) void k_node_l2_fused(
    const float* __restrict__ S, const unsigned* __restrict__ cnt,
    const ushort* __restrict__ W12h, const ushort* __restrict__ W12l,
    const float* __restrict__ b12,
    const ushort* __restrict__ W21h, const ushort* __restrict__ W21l,
    const float* __restrict__ b21,
    float* __restrict__ A, ushort* __restrict__ Bb) {
  __shared__ __align__(16) ushort s_hi[64 * 128];
  __shared__ __align__(16) ushort s_lo[64 * 128];
  __shared__ float s_m[64 * 132];
  __shared__ float s_scale[64];
  __shared__ float s_alive[64];
  const int tid = threadIdx.x;
  const int nb = blockIdx.x * 64;
  if (tid < 64) {
    const int n = nb + tid;
    const unsigned c = (n < NNODES) ? cnt[n] : 0u;
    s_scale[tid] = c ? 1.f / (float)c : 0.f;
    s_alive[tid] = c ? 1.f : 0.f;
  }
  __syncthreads();

  // stage S*scale -> split LDS
  #pragma unroll
  for (int it = 0; it < 4; ++it) {
    const int idx = tid + it * 256;
    const int row = idx >> 4;
    const int kg8 = idx & 15;
    const int n = nb + row;
    float v[8];
    if (n < NNODES) {
      const float sc = s_scale[row];
      const float* p = S + (size_t)n * HDIM + kg8 * 8;
      const float4 a0 = *(const float4*)p;
      const float4 a1 = *(const float4*)(p + 4);
      v[0] = a0.x * sc; v[1] = a0.y * sc; v[2] = a0.z * sc; v[3] = a0.w * sc;
      v[4] = a1.x * sc; v[5] = a1.y * sc; v[6] = a1.z * sc; v[7] = a1.w * sc;
    } else {
      #pragma unroll
      for (int j = 0; j < 8; ++j) v[j] = 0.f;
    }
    short8 hv, lv;
    split8_tr(v, hv, lv);
    const int unit = row * 16 + (kg8 ^ (row & 15));
    *(short8*)(s_hi + unit * 8) = hv;
    *(short8*)(s_lo + unit * 8) = lv;
  }
  __syncthreads();

  const int l15 = tid & 15;
  const int l4  = (tid >> 4) & 3;
  const int w   = tid >> 6;

  // ---- GEMM1: 128 cols (2 ctl/wave) ----
  {
    f32x4 acc[4][2];
    #pragma unroll
    for (int rt = 0; rt < 4; ++rt)
      #pragma unroll
      for (int c = 0; c < 2; ++c)
        #pragma unroll
        for (int r = 0; r < 4; ++r) acc[rt][c][r] = 0.f;

    #pragma unroll
    for (int ks = 0; ks < 4; ++ks) {
      short8 wh[2], wl[2];
      #pragma unroll
      for (int ctl = 0; ctl < 2; ++ctl) {
        const int ct_g = w * 2 + ctl;
        const size_t u = ((size_t)(((ct_g * 4 + ks) * 4 + l4) * 16 + l15)) * 8;
        wh[ctl] = *(const short8*)(W12h + u);
        wl[ctl] = *(const short8*)(W12l + u);
      }
      #pragma unroll
      for (int rt = 0; rt < 4; ++rt) {
        const int unit = (rt * 16 + l15) * 16 + ((ks * 4 + l4) ^ l15);
        const short8 ah = *(const short8*)(s_hi + unit * 8);
        const short8 al = *(const short8*)(s_lo + unit * 8);
        #pragma unroll
        for (int ctl = 0; ctl < 2; ++ctl) {
          acc[rt][ctl] = __builtin_amdgcn_mfma_f32_16x16x32_bf16(al, wh[ctl], acc[rt][ctl], 0, 0, 0);
          acc[rt][ctl] = __builtin_amdgcn_mfma_f32_16x16x32_bf16(ah, wl[ctl], acc[rt][ctl], 0, 0, 0);
          acc[rt][ctl] = __builtin_amdgcn_mfma_f32_16x16x32_bf16(ah, wh[ctl], acc[rt][ctl], 0, 0, 0);
        }
      }
    }

    // dump h2 = relu(acc+bias)*alive to s_m
    const float bb0 = b12[w * 32 + l15];
    const float bb1 = b12[w * 32 + 16 + l15];
    #pragma unroll
    for (int rt = 0; rt < 4; ++rt)
      #pragma unroll
      for (int ctl = 0; ctl < 2; ++ctl)
        #pragma unroll
        for (int r = 0; r < 4; ++r) {
          const int row = rt * 16 + l4 * 4 + r;
          s_m[row * 132 + w * 32 + ctl * 16 + l15] =
              fmaxf(acc[rt][ctl][r] + (ctl ? bb1 : bb0), 0.f) * s_alive[row];
        }
  }
  __syncthreads();  // all GEMM1 LDS reads + s_m writes done

  // restage h2 -> split LDS (overwrite s_hi/s_lo)
  #pragma unroll
  for (int it = 0; it < 4; ++it) {
    const int idx = tid + it * 256;
    const int row = idx >> 4;
    const int kg8 = idx & 15;
    const float* p = s_m + row * 132 + kg8 * 8;
    float v[8];
    const float4 a0 = *(const float4*)p;
    const float4 a1 = *(const float4*)(p + 4);
    v[0] = a0.x; v[1] = a0.y; v[2] = a0.z; v[3] = a0.w;
    v[4] = a1.x; v[5] = a1.y; v[6] = a1.z; v[7] = a1.w;
    short8 hv, lv;
    split8_tr(v, hv, lv);
    const int unit = row * 16 + (kg8 ^ (row & 15));
    *(short8*)(s_hi + unit * 8) = hv;
    *(short8*)(s_lo + unit * 8) = lv;
  }
  __syncthreads();

  // ---- GEMM2: 256 cols (4 ctl/wave) ----
  f32x4 acc2[4][4];
  #pragma unroll
  for (int rt = 0; rt < 4; ++rt)
    #pragma unroll
    for (int c = 0; c < 4; ++c)
      #pragma unroll
      for (int r = 0; r < 4; ++r) acc2[rt][c][r] = 0.f;

  #pragma unroll
  for (int ks = 0; ks < 4; ++ks) {
    short8 wh[4], wl[4];
    #pragma unroll
    for (int ctl = 0; ctl < 4; ++ctl) {
      const int ct_g = w * 4 + ctl;
      const size_t u = ((size_t)(((ct_g * 4 + ks) * 4 + l4) * 16 + l15)) * 8;
      wh[ctl] = *(const short8*)(W21h + u);
      wl[ctl] = *(const short8*)(W21l + u);
    }
    #pragma unroll
    for (int rt = 0; rt < 4; ++rt) {
      const int unit = (rt * 16 + l15) * 16 + ((ks * 4 + l4) ^ l15);
      const short8 ah = *(const short8*)(s_hi + unit * 8);
      const short8 al = *(const short8*)(s_lo + unit * 8);
      #pragma unroll
      for (int ctl = 0; ctl < 4; ++ctl) {
        acc2[rt][ctl] = __builtin_amdgcn_mfma_f32_16x16x32_bf16(al, wh[ctl], acc2[rt][ctl], 0, 0, 0);
        acc2[rt][ctl] = __builtin_amdgcn_mfma_f32_16x16x32_bf16(ah, wl[ctl], acc2[rt][ctl], 0, 0, 0);
        acc2[rt][ctl] = __builtin_amdgcn_mfma_f32_16x16x32_bf16(ah, wh[ctl], acc2[rt][ctl], 0, 0, 0);
      }
    }
  }

  #pragma unroll
  for (int ctl = 0; ctl < 4; ++ctl) {
    const int col_g = w * 64 + ctl * 16 + l15;
    if (col_g < HDIM) {
      const float bias = b21[col_g];
      #pragma unroll
      for (int rt = 0; rt < 4; ++rt)
        #pragma unroll
        for (int r = 0; r < 4; ++r) {
          const int n = nb + rt * 16 + l4 * 4 + r;
          if (n < NNODES) A[(size_t)n * HDIM + col_g] = acc2[rt][ctl][r] + bias;
        }
    } else {
      const int cb = col_g - HDIM;
      #pragma unroll
      for (int rt = 0; rt < 4; ++rt)
        #pragma unroll
        for (int r = 0; r < 4; ++r) {
          const int n = nb + rt * 16 + l4 * 4 + r;
          if (n < NNODES) Bb[(size_t)n * HDIM + cb] = bf16_rne(acc2[rt][ctl][r]);
        }
    }
  }
}

// ---------------- layer 0: split-bf16 MFMA edge GEMM + LDS segmented max ----
// B0 gathered as bf16 rows (half the random-gather bytes); A0 fp32 (L1-hot).
__global__ __launch_bounds__(256) void k_edge_l0_mfma(
    const float* __restrict__ A0, const ushort* __restrict__ B0b,
    const int* __restrict__ ssrc, const int* __restrict__ sdst,
    const ushort* __restrict__ Whi, const ushort* __restrict__ Wlo,
    const float* __restrict__ b2, unsigned* __restrict__ outenc) {
  __shared__ __align__(16) char s_un[4 * 64 * 33 * 4];
  __shared__ int s_dstA[64];
  __shared__ int s_srcA[64];
  ushort* s_thi = (ushort*)s_un;
  ushort* s_tlo = (ushort*)(s_un + 16384);
  float*  s_m   = (float*)s_un;

  const int tid = threadIdx.x;
  const int eb = blockIdx.x * 64;
  if (tid < 64) s_dstA[tid] = sdst[eb + tid];
  else if (tid < 128) s_srcA[tid - 64] = ssrc[eb + tid - 64];
  __syncthreads();

  #pragma unroll
  for (int it = 0; it < 4; ++it) {
    const int idx = tid + it * 256;
    const int e = idx >> 4;
    const int kg8 = idx & 15;
    const int k0 = kg8 * 8;
    const float* ap = A0 + (size_t)s_dstA[e] * HDIM + k0;
    const ushort* bp = B0b + (size_t)s_srcA[e] * HDIM + k0;
    const float4 a0 = *(const float4*)ap;
    const float4 a1 = *(const float4*)(ap + 4);
    const short8 b8 = *(const short8*)bp;
    const float af[8] = {a0.x, a0.y, a0.z, a0.w, a1.x, a1.y, a1.z, a1.w};
    float v[8];
    #pragma unroll
    for (int j = 0; j < 8; ++j) {
      const float bv = __uint_as_float(((unsigned)(ushort)b8[j]) << 16);
      v[j] = fmaxf(af[j] + bv, 0.f);
    }
    short8 hv, lv;
    split8_tr(v, hv, lv);
    const int unit = e * 16 + (kg8 ^ (e & 15));
    *(short8*)(s_thi + unit * 8) = hv;
    *(short8*)(s_tlo + unit * 8) = lv;
  }
  __syncthreads();

  const int l15 = tid & 15;
  const int l4  = (tid >> 4) & 3;
  const int w   = tid >> 6;

  f32x4 acc[4][2];
  #pragma unroll
  for (int rt = 0; rt < 4; ++rt)
    #pragma unroll
    for (int c = 0; c < 2; ++c)
      #pragma unroll
      for (int r = 0; r < 4; ++r) acc[rt][c][r] = 0.f;

  #pragma unroll
  for (int ks = 0; ks < 4; ++ks) {
    short8 wh[2], wl[2];
    #pragma unroll
    for (int ctl = 0; ctl < 2; ++ctl) {
      const int ct_g = w * 2 + ctl;
      const size_t u = ((size_t)(((ct_g * 4 + ks) * 4 + l4) * 16 + l15)) * 8;
      wh[ctl] = *(const short8*)(Whi + u);
      wl[ctl] = *(const short8*)(Wlo + u);
    }
    #pragma unroll
    for (int rt = 0; rt < 4; ++rt) {
      const int e = rt * 16 + l15;
      const int unit = e * 16 + ((ks * 4 + l4) ^ l15);
      const short8 ah = *(const short8*)(s_thi + unit * 8);
      const short8 al = *(const short8*)(s_tlo + unit * 8);
      #pragma unroll
      for (int ctl = 0; ctl < 2; ++ctl) {
        acc[rt][ctl] = __builtin_amdgcn_mfma_f32_16x16x32_bf16(al, wh[ctl], acc[rt][ctl], 0, 0, 0);
        acc[rt][ctl] = __builtin_amdgcn_mfma_f32_16x16x32_bf16(ah, wl[ctl], acc[rt][ctl], 0, 0, 0);
        acc[rt][ctl] = __builtin_amdgcn_mfma_f32_16x16x32_bf16(ah, wh[ctl], acc[rt][ctl], 0, 0, 0);
      }
    }
  }
  __syncthreads();

  const float bb0 = b2[w * 32 + l15];
  const float bb1 = b2[w * 32 + 16 + l15];
  float* sm = s_m + w * (64 * 33);
  #pragma unroll
  for (int rt = 0; rt < 4; ++rt)
    #pragma unroll
    for (int ctl = 0; ctl < 2; ++ctl)
      #pragma unroll
      for (int r = 0; r < 4; ++r)
        sm[(rt * 16 + l4 * 4 + r) * 33 + ctl * 16 + l15] =
            acc[rt][ctl][r] + (ctl ? bb1 : bb0);
  __syncthreads();

  {
    const int l = tid & 63;
    const int col = l & 31;
    const int g = l >> 5;
    const int e0 = g * 32;
    int curd = s_dstA[e0];
    float run = sm[e0 * 33 + col];
    for (int e = e0 + 1; e < e0 + 32; ++e) {
      const int d = s_dstA[e];
      const float v = sm[e * 33 + col];
      if (d == curd) run = fmaxf(run, v);
      else {
        atomicMax(outenc + (size_t)curd * HDIM + w * 32 + col, enc_f32(run));
        curd = d; run = v;
      }
    }
    atomicMax(outenc + (size_t)curd * HDIM + w * 32 + col, enc_f32(run));
  }
}

// ---------------- layer-1 mean: wave-per-node CSR sum, bf16 B rows ----------
__global__ __launch_bounds__(256) void k_seg_mean(const float* __restrict__ A,
                                                  const ushort* __restrict__ B,
                                                  const int* __restrict__ ssrc,
                                                  const unsigned* __restrict__ endv,
                                                  const unsigned* __restrict__ cnt,
                                                  float* __restrict__ S) {
  const int tid = threadIdx.x;
  const int n = blockIdx.x * 4 + (tid >> 6);
  const int lane = tid & 63;
  const unsigned end = endv[n];
  unsigned e = end - cnt[n];
  const float2 a = *(const float2*)(A + (size_t)n * HDIM + lane * 2);
  float sx = 0.f, sy = 0.f;
  for (; e + 8 <= end; e += 8) {
    int s[8];
    #pragma unroll
    for (int k = 0; k < 8; ++k) s[k] = ssrc[e + k];
    unsigned bv[8];
    #pragma unroll
    for (int k = 0; k < 8; ++k)
      bv[k] = *(const unsigned*)(B + (size_t)s[k] * HDIM + lane * 2);
    #pragma unroll
    for (int k = 0; k < 8; ++k) {
      sx += fmaxf(a.x + __uint_as_float(bv[k] << 16), 0.f);
      sy += fmaxf(a.y + __uint_as_float(bv[k] & 0xffff0000u), 0.f);
    }
  }
  for (; e < end; ++e) {
    const unsigned bv = *(const unsigned*)(B + (size_t)ssrc[e] * HDIM + lane * 2);
    sx += fmaxf(a.x + __uint_as_float(bv << 16), 0.f);
    sy += fmaxf(a.y + __uint_as_float(bv & 0xffff0000u), 0.f);
  }
  float2 o; o.x = sx; o.y = sy;
  *(float2*)(S + (size_t)n * HDIM + lane * 2) = o;
}

// ---------------- layer-2 mean fused with final fc --------------------------
// out[n] = (mean_e relu(A2[n]+B2[src])) @ Wfold + bfold ; deg==0 -> bf
__global__ __launch_bounds__(256) void k_seg_final(const float* __restrict__ A,
                                                   const ushort* __restrict__ B,
                                                   const int* __restrict__ ssrc,
                                                   const unsigned* __restrict__ endv,
                                                   const unsigned* __restrict__ cnt,
                                                   const float* __restrict__ Wfold,
                                                   const float* __restrict__ bfold,
                                                   const float* __restrict__ bf,
                                                   float* __restrict__ out) {
  const int tid = threadIdx.x;
  const int n = blockIdx.x * 4 + (tid >> 6);
  const int lane = tid & 63;
  const unsigned deg = cnt[n];
  if (deg == 0) {
    if (lane == 0) {
      float4 o; o.x = bf[0]; o.y = bf[1]; o.z = bf[2]; o.w = bf[3];
      ((float4*)out)[n] = o;
    }
    return;
  }
  const unsigned end = endv[n];
  unsigned e = end - deg;
  const float2 a = *(const float2*)(A + (size_t)n * HDIM + lane * 2);
  float sx = 0.f, sy = 0.f;
  for (; e + 8 <= end; e += 8) {
    int s[8];
    #pragma unroll
    for (int k = 0; k < 8; ++k) s[k] = ssrc[e + k];
    unsigned bv[8];
    #pragma unroll
    for (int k = 0; k < 8; ++k)
      bv[k] = *(const unsigned*)(B + (size_t)s[k] * HDIM + lane * 2);
    #pragma unroll
    for (int k = 0; k < 8; ++k) {
      sx += fmaxf(a.x + __uint_as_float(bv[k] << 16), 0.f);
      sy += fmaxf(a.y + __uint_as_float(bv[k] & 0xffff0000u), 0.f);
    }
  }
  for (; e < end; ++e) {
    const unsigned bv = *(const unsigned*)(B + (size_t)ssrc[e] * HDIM + lane * 2);
    sx += fmaxf(a.x + __uint_as_float(bv << 16), 0.f);
    sy += fmaxf(a.y + __uint_as_float(bv & 0xffff0000u), 0.f);
  }
  const float inv = 1.f / (float)deg;
  const float vx = sx * inv, vy = sy * inv;
  const float4 w0 = ((const float4*)Wfold)[lane * 2];
  const float4 w1 = ((const float4*)Wfold)[lane * 2 + 1];
  float p0 = fmaf(vx, w0.x, vy * w1.x);
  float p1 = fmaf(vx, w0.y, vy * w1.y);
  float p2 = fmaf(vx, w0.z, vy * w1.z);
  float p3 = fmaf(vx, w0.w, vy * w1.w);
  #pragma unroll
  for (int off = 32; off; off >>= 1) {
    p0 += __shfl_xor(p0, off);
    p1 += __shfl_xor(p1, off);
    p2 += __shfl_xor(p2, off);
    p3 += __shfl_xor(p3, off);
  }
  if (lane == 0) {
    float4 o;
    o.x = p0 + bfold[0]; o.y = p1 + bfold[1];
    o.z = p2 + bfold[2]; o.w = p3 + bfold[3];
    ((float4*)out)[n] = o;
  }
}

// ----------------------------------------------------------------------------
extern "C" void kernel_launch(void* const* d_in, const int* in_sizes, int n_in,
                              void* d_out, int out_size, void* d_ws, size_t ws_size,
                              hipStream_t stream) {
  const float* x   = (const float*)d_in[0];
  // d_in[1] = edge_attr: unused in math
  const int*   eidx = (const int*)d_in[2];
  const float* W01 = (const float*)d_in[3];
  const float* b01 = (const float*)d_in[4];
  const float* W02 = (const float*)d_in[5];
  const float* b02 = (const float*)d_in[6];
  const float* W11 = (const float*)d_in[7];
  const float* b11 = (const float*)d_in[8];
  const float* W12 = (const float*)d_in[9];
  const float* b12 = (const float*)d_in[10];
  const float* W21 = (const float*)d_in[11];
  const float* b21 = (const float*)d_in[12];
  const float* W22 = (const float*)d_in[13];
  const float* b22 = (const float*)d_in[14];
  const float* Wf  = (const float*)d_in[15];
  const float* bf  = (const float*)d_in[16];
  float* out = (float*)d_out;
  char* ws = (char*)d_ws;

  float* buf0 = (float*)(ws + OFF_BUF0);
  float* buf1 = (float*)(ws + OFF_BUF1);
  float* buf2 = (float*)(ws + OFF_BUF2);
  ushort* bufB = (ushort*)(ws + OFF_BFB);
  unsigned* cnt    = (unsigned*)(ws + OFF_CNT);
  unsigned* cursor = (unsigned*)(ws + OFF_CUR);
  unsigned* csum   = (unsigned*)(ws + OFF_CSUM);
  unsigned* coff   = (unsigned*)(ws + OFF_COFF);
  float* Wfold = (float*)(ws + OFF_WFOLD);
  float* bfold = (float*)(ws + OFF_BFOLD);
  int* flag  = (int*)(ws + OFF_FLAG);
  int* ssrc  = (int*)(ws + OFF_SSRC);
  int* sdst  = (int*)(ws + OFF_SDST);
  ushort* W02h = (ushort*)(ws + OFF_W02H);
  ushort* W02l = (ushort*)(ws + OFF_W02L);
  ushort* W12h = (ushort*)(ws + OFF_W12H);
  ushort* W12l = (ushort*)(ws + OFF_W12L);
  ushort* W11h = (ushort*)(ws + OFF_W11H);
  ushort* W11l = (ushort*)(ws + OFF_W11L);
  ushort* W21h = (ushort*)(ws + OFF_W21H);
  ushort* W21l = (ushort*)(ws + OFF_W21L);

  // ---- counting sort of edges by dst (CSR) + weight prep ----
  k_init<<<NPAD / 256, 256, 0, stream>>>(eidx, flag, cnt);
  k_count<<<NEDGES / 256, 256, 0, stream>>>(eidx, flag, cnt);
  k_scan1<<<NCH, 256, 0, stream>>>(cnt, csum);
  k_scan2<<<1, 64, 0, stream>>>(csum, coff);
  k_scan3<<<NCH, 256, 0, stream>>>(cnt, coff, cursor);
  k_scatter<<<NEDGES / 256, 256, 0, stream>>>(eidx, flag, cursor, ssrc, sdst);
  // after scatter: cursor[n] == segment end offset of node n
  k_prep_all<<<50, 256, 0, stream>>>(W02, W12, W11, W21, W22, Wf, b22, bf,
                                     W02h, W02l, W12h, W12l, W11h, W11l,
                                     W21h, W21l, Wfold, bfold);

  // ---- layer 0 (max aggr) ----
  k_node_ab16<<<NNODES / 16, 256, 0, stream>>>(x, W01, b01, buf0, bufB);
  hipMemsetAsync(buf2, 0, NHB, stream);
  k_edge_l0_mfma<<<NEDGES / 64, 256, 0, stream>>>(buf0, bufB, ssrc, sdst,
                                                  W02h, W02l, b02, (unsigned*)buf2);
  // buf2 = encoded h1 (decode fused into next stage)

  // ---- layer 1 (mean aggr) ----
  k_node_ab_mfma<<<NBLK64, 256, 0, stream>>>((const unsigned*)buf2, W11h, W11l,
                                             b11, buf0, bufB);
  k_seg_mean<<<NNODES / 4, 256, 0, stream>>>(buf0, bufB, ssrc, cursor, cnt, buf1);

  // ---- layer 2: h2-GEMM + A2|B2-GEMM fused, then mean+final fused ----
  k_node_l2_fused<<<NBLK64, 256, 0, stream>>>(buf1, cnt, W12h, W12l, b12,
                                              W21h, W21l, b21, buf0, bufB);
  k_seg_final<<<NNODES / 4, 256, 0, stream>>>(buf0, bufB, ssrc, cursor, cnt,
                                              Wfold, bfold, bf, out);

  (void)in_sizes; (void)n_in; (void)out_size; (void)ws_size;
}